// Round 1
// baseline (476.809 us; speedup 1.0000x reference)
//
#include <hip/hip_runtime.h>
#include <hip/hip_bf16.h>
#include <cstddef>

// Problem constants (B, D, CL, QL) = (32, 128, 1024, 512)
#define B_  32
#define D_  128
#define CL_ 1024
#define QL_ 512

// ---------------------------------------------------------------------------
// Kernel 1: U[c,d] = wq[c,d] + wqc[c,d] * Ct[c,d];  bias[c] = sum_d wc[c,d]*Ct[c,d]
// Ct[c,d] = C[b,d,c]. Transpose-stage a 128d x 32c tile of C through LDS.
// ---------------------------------------------------------------------------
__global__ __launch_bounds__(256) void k_u_bias(const float* __restrict__ C,
                                                const float* __restrict__ W,
                                                float* __restrict__ U,
                                                float* __restrict__ bias) {
    int b  = blockIdx.y;
    int c0 = blockIdx.x * 32;
    int tid = threadIdx.x;

    __shared__ float tile[128][33];   // [d][c], +1 pad
    __shared__ float bred[32][9];

    // Coalesced load: 32 consecutive c per 32 lanes, 8 d-rows per pass
    for (int pass = 0; pass < 16; ++pass) {
        int d = pass * 8 + (tid >> 5);
        int c = tid & 31;
        tile[d][c] = C[((size_t)(b * D_ + d)) * CL_ + c0 + c];
    }
    __syncthreads();

    int tc    = tid >> 3;   // 0..31 local c
    int lane8 = tid & 7;    // 0..7
    int c     = c0 + tc;
    size_t wbase = ((size_t)(b * CL_ + c)) * (3 * D_);
    size_t ubase = ((size_t)(b * CL_ + c)) * D_;

    float bpart = 0.f;
    for (int i = 0; i < 16; ++i) {
        int d = lane8 + i * 8;
        float ct   = tile[d][tc];
        float wqv  = W[wbase + d];
        float wcv  = W[wbase + D_ + d];
        float wqcv = W[wbase + 2 * D_ + d];
        U[ubase + d] = wqv + wqcv * ct;
        bpart += wcv * ct;
    }
    bred[tc][lane8] = bpart;
    __syncthreads();
    if (lane8 == 0) {
        float s = 0.f;
        for (int i = 0; i < 8; ++i) s += bred[tc][i];
        bias[b * CL_ + c] = s;
    }
}

// ---------------------------------------------------------------------------
// Kernel 2: S[c,q] = sum_d U[c,d]*Q[b,d,q] + bias[c]   (NN GEMM, M=CL,N=QL,K=D)
// 64x64 block tile, 256 threads, 4x4 micro-tile, BK=16.
// ---------------------------------------------------------------------------
__global__ __launch_bounds__(256) void k_s_gemm(const float* __restrict__ U,
                                                const float* __restrict__ Q,
                                                const float* __restrict__ bias,
                                                float* __restrict__ S) {
    int b  = blockIdx.z;
    int m0 = blockIdx.y * 64;   // c
    int n0 = blockIdx.x * 64;   // q
    int tid = threadIdx.x;

    __shared__ float As[16][68];  // [k][m]
    __shared__ float Bs[16][68];  // [k][n]

    float acc[4][4] = {};
    int ty = tid >> 4, tx = tid & 15;

    const float* Ab = U + (size_t)(b * CL_ + m0) * D_;
    const float* Bb = Q + (size_t)b * D_ * QL_ + n0;

    int lr    = tid >> 2;         // 0..63
    int lc4   = (tid & 3) * 4;    // 0,4,8,12
    int brow  = tid >> 4;         // 0..15
    int bcol4 = (tid & 15) * 4;   // 0..60

    for (int k0 = 0; k0 < D_; k0 += 16) {
        float4 a = *(const float4*)(Ab + (size_t)lr * D_ + k0 + lc4);
        As[lc4 + 0][lr] = a.x;
        As[lc4 + 1][lr] = a.y;
        As[lc4 + 2][lr] = a.z;
        As[lc4 + 3][lr] = a.w;
        float4 bq = *(const float4*)(Bb + (size_t)(k0 + brow) * QL_ + bcol4);
        *(float4*)&Bs[brow][bcol4] = bq;
        __syncthreads();
        for (int k = 0; k < 16; ++k) {
            float am[4], bn[4];
            *(float4*)am = *(const float4*)&As[k][ty * 4];
            *(float4*)bn = *(const float4*)&Bs[k][tx * 4];
            #pragma unroll
            for (int i = 0; i < 4; ++i)
                #pragma unroll
                for (int j = 0; j < 4; ++j)
                    acc[i][j] += am[i] * bn[j];
        }
        __syncthreads();
    }

    for (int i = 0; i < 4; ++i) {
        int m = m0 + ty * 4 + i;
        float bv = bias[b * CL_ + m];
        float4 o;
        o.x = acc[i][0] + bv; o.y = acc[i][1] + bv;
        o.z = acc[i][2] + bv; o.w = acc[i][3] + bv;
        *(float4*)(S + (size_t)(b * CL_ + m) * QL_ + n0 + tx * 4) = o;
    }
}

// ---------------------------------------------------------------------------
// Kernel 3: row softmax stats over q (512) per row (b*CL+c). One wave per row.
// ---------------------------------------------------------------------------
__global__ __launch_bounds__(64) void k_row_stats(const float* __restrict__ S,
                                                  float* __restrict__ rmax,
                                                  float* __restrict__ rinv) {
    int row  = blockIdx.x;        // b*CL + c
    int lane = threadIdx.x;       // 0..63
    const float* Sr = S + (size_t)row * QL_;
    float4 v0 = *(const float4*)(Sr + lane * 4);
    float4 v1 = *(const float4*)(Sr + 256 + lane * 4);
    float m = fmaxf(fmaxf(fmaxf(v0.x, v0.y), fmaxf(v0.z, v0.w)),
                    fmaxf(fmaxf(v1.x, v1.y), fmaxf(v1.z, v1.w)));
    for (int off = 32; off; off >>= 1) m = fmaxf(m, __shfl_xor(m, off));
    float s = __expf(v0.x - m) + __expf(v0.y - m) + __expf(v0.z - m) + __expf(v0.w - m)
            + __expf(v1.x - m) + __expf(v1.y - m) + __expf(v1.z - m) + __expf(v1.w - m);
    for (int off = 32; off; off >>= 1) s += __shfl_xor(s, off);
    if (lane == 0) { rmax[row] = m; rinv[row] = 1.0f / s; }
}

// ---------------------------------------------------------------------------
// Kernel 4: column softmax stats over c (1024) per (b,q). Online max+sum.
// Block: 64 q-columns x 4 c-chunks; coalesced over q.
// ---------------------------------------------------------------------------
__global__ __launch_bounds__(256) void k_col_stats(const float* __restrict__ S,
                                                   float* __restrict__ cmax,
                                                   float* __restrict__ cinv) {
    int b   = blockIdx.y;
    int q0  = blockIdx.x * 64;
    int tid = threadIdx.x;
    int qi  = tid & 63;
    int cch = tid >> 6;   // 0..3
    const float* Sb = S + (size_t)b * CL_ * QL_ + q0 + qi;

    float m = -1e30f, s = 0.f;
    for (int c = cch * 256; c < cch * 256 + 256; ++c) {
        float v = Sb[(size_t)c * QL_];
        if (v > m) { s = s * __expf(m - v) + 1.0f; m = v; }
        else       { s += __expf(v - m); }
    }
    __shared__ float lm[4][64], ls[4][64];
    lm[cch][qi] = m; ls[cch][qi] = s;
    __syncthreads();
    if (cch == 0) {
        float M = m, SS = s;
        for (int i = 1; i < 4; ++i) {
            float mi = lm[i][qi], si = ls[i][qi];
            float nM = fmaxf(M, mi);
            SS = SS * __expf(M - nM) + si * __expf(mi - nM);
            M = nM;
        }
        cmax[b * QL_ + q0 + qi] = M;
        cinv[b * QL_ + q0 + qi] = 1.0f / SS;
    }
}

// ---------------------------------------------------------------------------
// Kernels 5/7: NT GEMM  Out[d,c] = sum_q A[d,q] * S1[c,q]
// S1 computed on the fly from S + row stats. M=D(128), N=CL(1024), K=QL(512).
// MODE 0 (A=Q): writes out rows [0,D)=Ct, [D,2D)=At, [2D,3D)=Ct*At
// MODE 1 (A=P): writes out rows [3D,4D)=Ct*Bmt
// ---------------------------------------------------------------------------
template <int MODE>
__global__ __launch_bounds__(256) void k_nt_gemm(const float* __restrict__ A,
                                                 const float* __restrict__ S,
                                                 const float* __restrict__ rmax,
                                                 const float* __restrict__ rinv,
                                                 const float* __restrict__ C,
                                                 float* __restrict__ out) {
    int b  = blockIdx.z;
    int m0 = blockIdx.y * 64;   // d
    int n0 = blockIdx.x * 64;   // c
    int tid = threadIdx.x;

    __shared__ float As[16][68];  // [k][m]
    __shared__ float Bs[16][68];  // [k][n]

    float acc[4][4] = {};
    int ty = tid >> 4, tx = tid & 15;

    const float* Ab = A + (size_t)b * D_ * QL_ + (size_t)m0 * QL_;
    const float* Sb = S + (size_t)(b * CL_ + n0) * QL_;

    int lr  = tid >> 2;        // 0..63
    int lc4 = (tid & 3) * 4;
    float rm = rmax[b * CL_ + n0 + lr];
    float ri = rinv[b * CL_ + n0 + lr];

    for (int k0 = 0; k0 < QL_; k0 += 16) {
        float4 a = *(const float4*)(Ab + (size_t)lr * QL_ + k0 + lc4);
        As[lc4 + 0][lr] = a.x;
        As[lc4 + 1][lr] = a.y;
        As[lc4 + 2][lr] = a.z;
        As[lc4 + 3][lr] = a.w;
        float4 sv = *(const float4*)(Sb + (size_t)lr * QL_ + k0 + lc4);
        Bs[lc4 + 0][lr] = __expf(sv.x - rm) * ri;
        Bs[lc4 + 1][lr] = __expf(sv.y - rm) * ri;
        Bs[lc4 + 2][lr] = __expf(sv.z - rm) * ri;
        Bs[lc4 + 3][lr] = __expf(sv.w - rm) * ri;
        __syncthreads();
        for (int k = 0; k < 16; ++k) {
            float am[4], bn[4];
            *(float4*)am = *(const float4*)&As[k][ty * 4];
            *(float4*)bn = *(const float4*)&Bs[k][tx * 4];
            #pragma unroll
            for (int i = 0; i < 4; ++i)
                #pragma unroll
                for (int j = 0; j < 4; ++j)
                    acc[i][j] += am[i] * bn[j];
        }
        __syncthreads();
    }

    for (int i = 0; i < 4; ++i) {
        int d  = m0 + ty * 4 + i;
        int cc = n0 + tx * 4;
        float4 ct = *(const float4*)(C + (size_t)(b * D_ + d) * CL_ + cc);
        float4 av;
        av.x = acc[i][0]; av.y = acc[i][1]; av.z = acc[i][2]; av.w = acc[i][3];
        if (MODE == 0) {
            *(float4*)(out + ((size_t)(b * 4 * D_ + d)) * CL_ + cc) = ct;
            *(float4*)(out + ((size_t)(b * 4 * D_ + D_ + d)) * CL_ + cc) = av;
            float4 p;
            p.x = ct.x * av.x; p.y = ct.y * av.y; p.z = ct.z * av.z; p.w = ct.w * av.w;
            *(float4*)(out + ((size_t)(b * 4 * D_ + 2 * D_ + d)) * CL_ + cc) = p;
        } else {
            float4 p;
            p.x = ct.x * av.x; p.y = ct.y * av.y; p.z = ct.z * av.z; p.w = ct.w * av.w;
            *(float4*)(out + ((size_t)(b * 4 * D_ + 3 * D_ + d)) * CL_ + cc) = p;
        }
    }
}

// ---------------------------------------------------------------------------
// Kernel 6: P[d,q] = sum_k C[b,d,k] * S2[k,q]   (NN GEMM, M=D,N=QL,K=CL)
// S2 computed on the fly from S + column stats.
// ---------------------------------------------------------------------------
__global__ __launch_bounds__(256) void k_p_gemm(const float* __restrict__ C,
                                                const float* __restrict__ S,
                                                const float* __restrict__ cmax,
                                                const float* __restrict__ cinv,
                                                float* __restrict__ P) {
    int b  = blockIdx.z;
    int m0 = blockIdx.y * 64;   // d
    int n0 = blockIdx.x * 64;   // q
    int tid = threadIdx.x;

    __shared__ float As[16][68];
    __shared__ float Bs[16][68];

    float acc[4][4] = {};
    int ty = tid >> 4, tx = tid & 15;

    const float* Ab = C + (size_t)(b * D_ + m0) * CL_;
    const float* Sb = S + (size_t)b * CL_ * QL_ + n0;

    int lr    = tid >> 2;
    int lc4   = (tid & 3) * 4;
    int brow  = tid >> 4;
    int bcol4 = (tid & 15) * 4;

    float4 cm = *(const float4*)(cmax + b * QL_ + n0 + bcol4);
    float4 ci = *(const float4*)(cinv + b * QL_ + n0 + bcol4);

    for (int k0 = 0; k0 < CL_; k0 += 16) {
        float4 a = *(const float4*)(Ab + (size_t)lr * CL_ + k0 + lc4);
        As[lc4 + 0][lr] = a.x;
        As[lc4 + 1][lr] = a.y;
        As[lc4 + 2][lr] = a.z;
        As[lc4 + 3][lr] = a.w;
        float4 sv = *(const float4*)(Sb + (size_t)(k0 + brow) * QL_ + bcol4);
        Bs[brow][bcol4 + 0] = __expf(sv.x - cm.x) * ci.x;
        Bs[brow][bcol4 + 1] = __expf(sv.y - cm.y) * ci.y;
        Bs[brow][bcol4 + 2] = __expf(sv.z - cm.z) * ci.z;
        Bs[brow][bcol4 + 3] = __expf(sv.w - cm.w) * ci.w;
        __syncthreads();
        for (int k = 0; k < 16; ++k) {
            float am[4], bn[4];
            *(float4*)am = *(const float4*)&As[k][ty * 4];
            *(float4*)bn = *(const float4*)&Bs[k][tx * 4];
            #pragma unroll
            for (int i = 0; i < 4; ++i)
                #pragma unroll
                for (int j = 0; j < 4; ++j)
                    acc[i][j] += am[i] * bn[j];
        }
        __syncthreads();
    }

    for (int i = 0; i < 4; ++i) {
        int m = m0 + ty * 4 + i;
        float4 o;
        o.x = acc[i][0]; o.y = acc[i][1]; o.z = acc[i][2]; o.w = acc[i][3];
        *(float4*)(P + (size_t)(b * D_ + m) * QL_ + n0 + tx * 4) = o;
    }
}

// ---------------------------------------------------------------------------
// Launch. Workspace layout (floats):
//   U:    B*CL*D      = 4,194,304
//   bias: B*CL        =    32,768
//   S:    B*CL*QL     = 16,777,216
//   rmax: B*CL        =    32,768
//   rinv: B*CL        =    32,768
//   cmax: B*QL        =    16,384
//   cinv: B*QL        =    16,384
//   P:    B*D*QL      = 2,097,152
// total ~93 MB
// ---------------------------------------------------------------------------
extern "C" void kernel_launch(void* const* d_in, const int* in_sizes, int n_in,
                              void* d_out, int out_size, void* d_ws, size_t ws_size,
                              hipStream_t stream) {
    const float* C = (const float*)d_in[0];
    const float* Q = (const float*)d_in[1];
    const float* W = (const float*)d_in[2];
    float* out = (float*)d_out;

    float* ws = (float*)d_ws;
    float* U    = ws;                     size_t off = (size_t)B_ * CL_ * D_;
    float* bias = ws + off;               off += (size_t)B_ * CL_;
    float* S    = ws + off;               off += (size_t)B_ * CL_ * QL_;
    float* rmax = ws + off;               off += (size_t)B_ * CL_;
    float* rinv = ws + off;               off += (size_t)B_ * CL_;
    float* cmax = ws + off;               off += (size_t)B_ * QL_;
    float* cinv = ws + off;               off += (size_t)B_ * QL_;
    float* P    = ws + off;

    k_u_bias<<<dim3(CL_ / 32, B_), 256, 0, stream>>>(C, W, U, bias);
    k_s_gemm<<<dim3(QL_ / 64, CL_ / 64, B_), 256, 0, stream>>>(U, Q, bias, S);
    k_row_stats<<<B_ * CL_, 64, 0, stream>>>(S, rmax, rinv);
    k_col_stats<<<dim3(QL_ / 64, B_), 256, 0, stream>>>(S, cmax, cinv);
    k_nt_gemm<0><<<dim3(CL_ / 64, D_ / 64, B_), 256, 0, stream>>>(Q, S, rmax, rinv, C, out);
    k_p_gemm<<<dim3(QL_ / 64, D_ / 64, B_), 256, 0, stream>>>(C, S, cmax, cinv, P);
    k_nt_gemm<1><<<dim3(CL_ / 64, D_ / 64, B_), 256, 0, stream>>>(P, S, rmax, rinv, C, out);
}

// Round 2
// 327.022 us; speedup vs baseline: 1.4580x; 1.4580x over previous
//
#include <hip/hip_runtime.h>
#include <hip/hip_bf16.h>
#include <cstddef>

// Problem constants (B, D, CL, QL) = (32, 128, 1024, 512)
#define B_  32
#define D_  128
#define CL_ 1024
#define QL_ 512

using short8  = __attribute__((ext_vector_type(8))) short;
using short4v = __attribute__((ext_vector_type(4))) short;
using float4v = __attribute__((ext_vector_type(4))) float;

__device__ __forceinline__ unsigned short f2bf(float f) {
    unsigned int u = __float_as_uint(f);
    u += 0x7FFFu + ((u >> 16) & 1u);   // RTNE
    return (unsigned short)(u >> 16);
}
__device__ __forceinline__ float bf2f(unsigned short h) {
    return __uint_as_float(((unsigned int)h) << 16);
}

// ---------------------------------------------------------------------------
// Kernel 1: Ubf[c,d] = bf16(wq + wqc*Ct); bias[c] = sum_d wc*Ct.  Ct via LDS
// transpose of C[b,d,c].
// ---------------------------------------------------------------------------
__global__ __launch_bounds__(256) void k_u_bias(const float* __restrict__ C,
                                                const float* __restrict__ W,
                                                unsigned short* __restrict__ U,
                                                float* __restrict__ bias) {
    int b  = blockIdx.y;
    int c0 = blockIdx.x * 32;
    int tid = threadIdx.x;

    __shared__ float tile[128][33];
    __shared__ float bred[32][9];

    for (int pass = 0; pass < 16; ++pass) {
        int d = pass * 8 + (tid >> 5);
        int c = tid & 31;
        tile[d][c] = C[((size_t)(b * D_ + d)) * CL_ + c0 + c];
    }
    __syncthreads();

    int tc    = tid >> 3;
    int lane8 = tid & 7;
    int c     = c0 + tc;
    size_t wbase = ((size_t)(b * CL_ + c)) * (3 * D_);
    size_t ubase = ((size_t)(b * CL_ + c)) * D_;

    float bpart = 0.f;
    for (int i = 0; i < 16; ++i) {
        int d = lane8 + i * 8;
        float ct   = tile[d][tc];
        float wqv  = W[wbase + d];
        float wcv  = W[wbase + D_ + d];
        float wqcv = W[wbase + 2 * D_ + d];
        U[ubase + d] = f2bf(wqv + wqcv * ct);
        bpart += wcv * ct;
    }
    bred[tc][lane8] = bpart;
    __syncthreads();
    if (lane8 == 0) {
        float s = 0.f;
        for (int i = 0; i < 8; ++i) s += bred[tc][i];
        bias[b * CL_ + c] = s;
    }
}

// ---------------------------------------------------------------------------
// Kernel 2: Qtbf[b,q,d] = bf16(Q[b,d,q])  (64x64 LDS transpose)
// ---------------------------------------------------------------------------
__global__ __launch_bounds__(256) void k_qt(const float* __restrict__ Q,
                                            unsigned short* __restrict__ Qt) {
    int b  = blockIdx.z;
    int d0 = blockIdx.y * 64;
    int q0 = blockIdx.x * 64;
    int tid = threadIdx.x;
    __shared__ float t[64][65];
    for (int p = 0; p < 16; ++p) {
        int d = p * 4 + (tid >> 6);
        int q = tid & 63;
        t[d][q] = Q[((size_t)(b * D_ + d0 + d)) * QL_ + q0 + q];
    }
    __syncthreads();
    for (int p = 0; p < 16; ++p) {
        int q  = p * 4 + (tid >> 6);
        int dd = tid & 63;
        Qt[((size_t)(b * QL_ + q0 + q)) * D_ + d0 + dd] = f2bf(t[dd][q]);
    }
}

// ---------------------------------------------------------------------------
// MFMA NT GEMM template: Out[m,n] = sum_k A[m,k]*B[n,k]
// 64x64 block tile, 4 waves (2x2), each wave 32x32 = 2x2 frags of 16x16x32.
// MODE 0: A=Ubf(bf16,lda=D)   B=Qtbf(ldb=D)   K=D    -> Sbf[c,q] (+bias)
// MODE 1: A=Q  (f32 ,lda=QL)  B=S1bf(ldb=QL)  K=QL   -> out rows [0,3D)
// MODE 2: A=C  (f32 ,lda=CL)  B=S2t (ldb=CL)  K=CL   -> Pbf[d,q]
// MODE 3: A=Pbf(bf16,lda=QL)  B=S1bf(ldb=QL)  K=QL   -> out rows [3D,4D)
// ---------------------------------------------------------------------------
template <int MODE, bool ABF16>
__global__ __launch_bounds__(256) void k_mfma_nt(const void* __restrict__ Av,
                                                 const unsigned short* __restrict__ Bm,
                                                 const float* __restrict__ bias,
                                                 const float* __restrict__ C,
                                                 unsigned short* __restrict__ Sbf,
                                                 float* __restrict__ out,
                                                 unsigned short* __restrict__ P) {
    constexpr int K = (MODE == 0) ? D_ : (MODE == 2 ? CL_ : QL_);
    constexpr int LDA = K;   // all operands are K-contiguous rows
    constexpr int LDB = K;
    constexpr size_t Astride = (MODE == 0) ? (size_t)CL_ * D_ : (size_t)D_ * K;
    constexpr size_t Bstride = (MODE == 0) ? (size_t)QL_ * D_
                             : (MODE == 2 ? (size_t)QL_ * CL_ : (size_t)CL_ * QL_);

    int b  = blockIdx.z;
    int n0 = blockIdx.x * 64;
    int m0 = blockIdx.y * 64;
    int tid  = threadIdx.x;
    int lane = tid & 63, wave = tid >> 6;
    int wm = wave >> 1, wn = wave & 1;
    int quad = lane >> 4, l15 = lane & 15;

    __shared__ __align__(16) short As[64][72];
    __shared__ __align__(16) short Bs[64][72];

    const unsigned short* Ab_bf = (const unsigned short*)Av + b * Astride + (size_t)m0 * LDA;
    const float*          Ab_f  = (const float*)Av          + b * Astride + (size_t)m0 * LDA;
    const unsigned short* Bb    = Bm + b * Bstride + (size_t)n0 * LDB;

    float4v acc[2][2] = {};

    for (int k0 = 0; k0 < K; k0 += 64) {
        // stage B (bf16)
        #pragma unroll
        for (int i = 0; i < 2; ++i) {
            int flat = tid + i * 256;
            int row = flat >> 3, col = (flat & 7) * 8;
            short8 v = *(const short8*)(Bb + (size_t)row * LDB + k0 + col);
            *(short8*)&Bs[row][col] = v;
        }
        // stage A
        if (ABF16) {
            #pragma unroll
            for (int i = 0; i < 2; ++i) {
                int flat = tid + i * 256;
                int row = flat >> 3, col = (flat & 7) * 8;
                short8 v = *(const short8*)(Ab_bf + (size_t)row * LDA + k0 + col);
                *(short8*)&As[row][col] = v;
            }
        } else {
            #pragma unroll
            for (int i = 0; i < 4; ++i) {
                int flat = tid + i * 256;
                int row = flat >> 4, col = (flat & 15) * 4;
                float4 a = *(const float4*)(Ab_f + (size_t)row * LDA + k0 + col);
                short4v p;
                p[0] = (short)f2bf(a.x); p[1] = (short)f2bf(a.y);
                p[2] = (short)f2bf(a.z); p[3] = (short)f2bf(a.w);
                *(short4v*)&As[row][col] = p;
            }
        }
        __syncthreads();
        #pragma unroll
        for (int ks = 0; ks < 64; ks += 32) {
            short8 af0 = *(const short8*)&As[wm * 32 + l15][ks + quad * 8];
            short8 af1 = *(const short8*)&As[wm * 32 + 16 + l15][ks + quad * 8];
            short8 bf0 = *(const short8*)&Bs[wn * 32 + l15][ks + quad * 8];
            short8 bf1 = *(const short8*)&Bs[wn * 32 + 16 + l15][ks + quad * 8];
            acc[0][0] = __builtin_amdgcn_mfma_f32_16x16x32_bf16(af0, bf0, acc[0][0], 0, 0, 0);
            acc[0][1] = __builtin_amdgcn_mfma_f32_16x16x32_bf16(af0, bf1, acc[0][1], 0, 0, 0);
            acc[1][0] = __builtin_amdgcn_mfma_f32_16x16x32_bf16(af1, bf0, acc[1][0], 0, 0, 0);
            acc[1][1] = __builtin_amdgcn_mfma_f32_16x16x32_bf16(af1, bf1, acc[1][1], 0, 0, 0);
        }
        __syncthreads();
    }

    #pragma unroll
    for (int fi = 0; fi < 2; ++fi)
        #pragma unroll
        for (int fj = 0; fj < 2; ++fj)
            #pragma unroll
            for (int r = 0; r < 4; ++r) {
                int m = m0 + wm * 32 + fi * 16 + quad * 4 + r;
                int n = n0 + wn * 32 + fj * 16 + l15;
                float v = acc[fi][fj][r];
                if (MODE == 0) {
                    v += bias[b * CL_ + m];
                    Sbf[((size_t)(b * CL_ + m)) * QL_ + n] = f2bf(v);
                } else if (MODE == 2) {
                    P[((size_t)(b * D_ + m)) * QL_ + n] = f2bf(v);
                } else {
                    float ct = C[((size_t)(b * D_ + m)) * CL_ + n];
                    if (MODE == 1) {
                        out[((size_t)(b * 4 * D_ + m)) * CL_ + n] = ct;
                        out[((size_t)(b * 4 * D_ + D_ + m)) * CL_ + n] = v;
                        out[((size_t)(b * 4 * D_ + 2 * D_ + m)) * CL_ + n] = ct * v;
                    } else {
                        out[((size_t)(b * 4 * D_ + 3 * D_ + m)) * CL_ + n] = ct * v;
                    }
                }
            }
}

// ---------------------------------------------------------------------------
// Kernel: row softmax stats over q per (b,c). One wave per row, bf16 S.
// ---------------------------------------------------------------------------
__global__ __launch_bounds__(64) void k_row_stats(const unsigned short* __restrict__ S,
                                                  float* __restrict__ rmax,
                                                  float* __restrict__ rinv) {
    int row  = blockIdx.x;
    int lane = threadIdx.x;
    const unsigned short* Sr = S + (size_t)row * QL_ + lane * 8;
    float v[8];
    uint4 raw = *(const uint4*)Sr;
    v[0] = bf2f(raw.x & 0xFFFF); v[1] = bf2f(raw.x >> 16);
    v[2] = bf2f(raw.y & 0xFFFF); v[3] = bf2f(raw.y >> 16);
    v[4] = bf2f(raw.z & 0xFFFF); v[5] = bf2f(raw.z >> 16);
    v[6] = bf2f(raw.w & 0xFFFF); v[7] = bf2f(raw.w >> 16);
    float m = v[0];
    #pragma unroll
    for (int i = 1; i < 8; ++i) m = fmaxf(m, v[i]);
    for (int off = 32; off; off >>= 1) m = fmaxf(m, __shfl_xor(m, off));
    float s = 0.f;
    #pragma unroll
    for (int i = 0; i < 8; ++i) s += __expf(v[i] - m);
    for (int off = 32; off; off >>= 1) s += __shfl_xor(s, off);
    if (lane == 0) { rmax[row] = m; rinv[row] = 1.0f / s; }
}

// ---------------------------------------------------------------------------
// Kernel: column softmax stats over c per (b,q). Online max+sum, bf16 S.
// ---------------------------------------------------------------------------
__global__ __launch_bounds__(256) void k_col_stats(const unsigned short* __restrict__ S,
                                                   float* __restrict__ cmax,
                                                   float* __restrict__ cinv) {
    int b   = blockIdx.y;
    int q0  = blockIdx.x * 64;
    int tid = threadIdx.x;
    int qi  = tid & 63;
    int cch = tid >> 6;
    const unsigned short* Sb = S + (size_t)b * CL_ * QL_ + q0 + qi;

    float m = -1e30f, s = 0.f;
    for (int c = cch * 256; c < cch * 256 + 256; ++c) {
        float v = bf2f(Sb[(size_t)c * QL_]);
        if (v > m) { s = s * __expf(m - v) + 1.0f; m = v; }
        else       { s += __expf(v - m); }
    }
    __shared__ float lm[4][64], ls[4][64];
    lm[cch][qi] = m; ls[cch][qi] = s;
    __syncthreads();
    if (cch == 0) {
        float M = m, SS = s;
        for (int i = 1; i < 4; ++i) {
            float mi = lm[i][qi], si = ls[i][qi];
            float nM = fmaxf(M, mi);
            SS = SS * __expf(M - nM) + si * __expf(mi - nM);
            M = nM;
        }
        cmax[b * QL_ + q0 + qi] = M;
        cinv[b * QL_ + q0 + qi] = 1.0f / SS;
    }
}

// ---------------------------------------------------------------------------
// Kernel: normalize — S1bf[c,q] = exp(s-rmax[c])*rinv[c];
//                     S2t[q,c] = exp(s-cmax[q])*cinv[q]  (LDS transpose)
// ---------------------------------------------------------------------------
__global__ __launch_bounds__(256) void k_normalize(const unsigned short* __restrict__ S,
                                                   const float* __restrict__ rmax,
                                                   const float* __restrict__ rinv,
                                                   const float* __restrict__ cmax,
                                                   const float* __restrict__ cinv,
                                                   unsigned short* __restrict__ S1,
                                                   unsigned short* __restrict__ S2t) {
    int b  = blockIdx.z;
    int c0 = blockIdx.y * 64;
    int q0 = blockIdx.x * 64;
    int tid = threadIdx.x;

    __shared__ __align__(16) short t[64][72];   // [c][q] of s2 (bf16 bits)
    __shared__ float scm[64], sci[64], srm[64], sri[64];

    if (tid < 64) {
        scm[tid] = cmax[b * QL_ + q0 + tid];
        sci[tid] = cinv[b * QL_ + q0 + tid];
        srm[tid] = rmax[b * CL_ + c0 + tid];
        sri[tid] = rinv[b * CL_ + c0 + tid];
    }
    __syncthreads();

    // phase 1: read S, write S1 (coalesced), stage s2 in LDS
    #pragma unroll
    for (int p = 0; p < 2; ++p) {
        int c  = p * 32 + (tid >> 3);
        int qb = (tid & 7) * 8;
        const unsigned short* Sp = S + ((size_t)(b * CL_ + c0 + c)) * QL_ + q0 + qb;
        uint4 raw = *(const uint4*)Sp;
        unsigned int rw[4] = {raw.x, raw.y, raw.z, raw.w};
        float rm = srm[c], ri = sri[c];
        short8 s1v, s2v;
        #pragma unroll
        for (int j = 0; j < 8; ++j) {
            unsigned short bits = (unsigned short)((rw[j >> 1] >> ((j & 1) * 16)) & 0xFFFF);
            float sv = bf2f(bits);
            s1v[j] = (short)f2bf(__expf(sv - rm) * ri);
            s2v[j] = (short)f2bf(__expf(sv - scm[qb + j]) * sci[qb + j]);
        }
        *(short8*)(S1 + ((size_t)(b * CL_ + c0 + c)) * QL_ + q0 + qb) = s1v;
        *(short8*)&t[c][qb] = s2v;
    }
    __syncthreads();
    // phase 2: write S2t transposed, lanes over c (coalesced)
    #pragma unroll
    for (int p = 0; p < 16; ++p) {
        int q = p * 4 + (tid >> 6);
        int c = tid & 63;
        S2t[((size_t)(b * QL_ + q0 + q)) * CL_ + c0 + c] = (unsigned short)t[c][q];
    }
}

// ---------------------------------------------------------------------------
// Launch. Workspace (bytes):
//   slotA (33.6 MB): Ubf [steps 1-3]  then S2t [steps 6-8]
//   slotB ( 4.2 MB): Qtbf [2-3]       then Pbf [8-9]
//   S1bf  (33.6 MB)
//   bias/rmax/rinv/cmax/cinv (~0.5 MB)
// Sbf (33.6 MB, bf16) lives in d_out (dead until step 7).     Total ~72 MB.
// ---------------------------------------------------------------------------
extern "C" void kernel_launch(void* const* d_in, const int* in_sizes, int n_in,
                              void* d_out, int out_size, void* d_ws, size_t ws_size,
                              hipStream_t stream) {
    const float* C = (const float*)d_in[0];
    const float* Q = (const float*)d_in[1];
    const float* W = (const float*)d_in[2];
    float* out = (float*)d_out;

    char* ws = (char*)d_ws;
    unsigned short* slotA = (unsigned short*)ws;                 // Ubf / S2t
    size_t slotA_elems = (size_t)B_ * CL_ * QL_;                 // 16.78M (covers both)
    unsigned short* slotB = slotA + slotA_elems;                 // Qtbf / Pbf
    size_t slotB_elems = (size_t)B_ * QL_ * D_;                  // 2.10M
    unsigned short* S1bf = slotB + slotB_elems;
    size_t s1_elems = (size_t)B_ * CL_ * QL_;
    float* bias = (float*)(S1bf + s1_elems);
    float* rmax = bias + (size_t)B_ * CL_;
    float* rinv = rmax + (size_t)B_ * CL_;
    float* cmax = rinv + (size_t)B_ * CL_;
    float* cinv = cmax + (size_t)B_ * QL_;

    unsigned short* Ubf  = slotA;
    unsigned short* S2t  = slotA;
    unsigned short* Qtbf = slotB;
    unsigned short* Pbf  = slotB;
    unsigned short* Sbf  = (unsigned short*)d_out;   // dead until G5 writes out

    k_u_bias<<<dim3(CL_ / 32, B_), 256, 0, stream>>>(C, W, Ubf, bias);
    k_qt<<<dim3(QL_ / 64, D_ / 64, B_), 256, 0, stream>>>(Q, Qtbf);
    k_mfma_nt<0, true><<<dim3(QL_ / 64, CL_ / 64, B_), 256, 0, stream>>>(
        Ubf, Qtbf, bias, C, Sbf, out, Pbf);
    k_row_stats<<<B_ * CL_, 64, 0, stream>>>(Sbf, rmax, rinv);
    k_col_stats<<<dim3(QL_ / 64, B_), 256, 0, stream>>>(Sbf, cmax, cinv);
    k_normalize<<<dim3(QL_ / 64, CL_ / 64, B_), 256, 0, stream>>>(
        Sbf, rmax, rinv, cmax, cinv, S1bf, S2t);
    k_mfma_nt<1, false><<<dim3(CL_ / 64, D_ / 64, B_), 256, 0, stream>>>(
        Q, S1bf, bias, C, Sbf, out, Pbf);
    k_mfma_nt<2, false><<<dim3(QL_ / 64, D_ / 64, B_), 256, 0, stream>>>(
        C, S2t, bias, C, Sbf, out, Pbf);
    k_mfma_nt<3, true><<<dim3(CL_ / 64, D_ / 64, B_), 256, 0, stream>>>(
        Pbf, S1bf, bias, C, Sbf, out, Pbf);
}

// Round 3
// 276.442 us; speedup vs baseline: 1.7248x; 1.1830x over previous
//
#include <hip/hip_runtime.h>
#include <hip/hip_bf16.h>
#include <cstddef>

// Problem constants (B, D, CL, QL) = (32, 128, 1024, 512)
#define B_  32
#define D_  128
#define CL_ 1024
#define QL_ 512

using short8  = __attribute__((ext_vector_type(8))) short;
using short4v = __attribute__((ext_vector_type(4))) short;
using float4v = __attribute__((ext_vector_type(4))) float;

__device__ __forceinline__ unsigned short f2bf(float f) {
    unsigned int u = __float_as_uint(f);
    u += 0x7FFFu + ((u >> 16) & 1u);   // RTNE
    return (unsigned short)(u >> 16);
}
__device__ __forceinline__ float bf2f(unsigned short h) {
    return __uint_as_float(((unsigned int)h) << 16);
}

// ---------------------------------------------------------------------------
// Kernel 1: Ubf[c,d] = bf16(wq + wqc*Ct); bias[c] = sum_d wc*Ct.  Ct via LDS
// transpose of C[b,d,c].
// ---------------------------------------------------------------------------
__global__ __launch_bounds__(256) void k_u_bias(const float* __restrict__ C,
                                                const float* __restrict__ W,
                                                unsigned short* __restrict__ U,
                                                float* __restrict__ bias) {
    int b  = blockIdx.y;
    int c0 = blockIdx.x * 32;
    int tid = threadIdx.x;

    __shared__ float tile[128][33];
    __shared__ float bred[32][9];

    for (int pass = 0; pass < 16; ++pass) {
        int d = pass * 8 + (tid >> 5);
        int c = tid & 31;
        tile[d][c] = C[((size_t)(b * D_ + d)) * CL_ + c0 + c];
    }
    __syncthreads();

    int tc    = tid >> 3;
    int lane8 = tid & 7;
    int c     = c0 + tc;
    size_t wbase = ((size_t)(b * CL_ + c)) * (3 * D_);
    size_t ubase = ((size_t)(b * CL_ + c)) * D_;

    float bpart = 0.f;
    for (int i = 0; i < 16; ++i) {
        int d = lane8 + i * 8;
        float ct   = tile[d][tc];
        float wqv  = W[wbase + d];
        float wcv  = W[wbase + D_ + d];
        float wqcv = W[wbase + 2 * D_ + d];
        U[ubase + d] = f2bf(wqv + wqcv * ct);
        bpart += wcv * ct;
    }
    bred[tc][lane8] = bpart;
    __syncthreads();
    if (lane8 == 0) {
        float s = 0.f;
        for (int i = 0; i < 8; ++i) s += bred[tc][i];
        bias[b * CL_ + c] = s;
    }
}

// ---------------------------------------------------------------------------
// Kernel 2: Qtbf[b,q,d] = bf16(Q[b,d,q])  (64x64 LDS transpose)
// ---------------------------------------------------------------------------
__global__ __launch_bounds__(256) void k_qt(const float* __restrict__ Q,
                                            unsigned short* __restrict__ Qt) {
    int b  = blockIdx.z;
    int d0 = blockIdx.y * 64;
    int q0 = blockIdx.x * 64;
    int tid = threadIdx.x;
    __shared__ float t[64][65];
    for (int p = 0; p < 16; ++p) {
        int d = p * 4 + (tid >> 6);
        int q = tid & 63;
        t[d][q] = Q[((size_t)(b * D_ + d0 + d)) * QL_ + q0 + q];
    }
    __syncthreads();
    for (int p = 0; p < 16; ++p) {
        int q  = p * 4 + (tid >> 6);
        int dd = tid & 63;
        Qt[((size_t)(b * QL_ + q0 + q)) * D_ + d0 + dd] = f2bf(t[dd][q]);
    }
}

// ---------------------------------------------------------------------------
// MFMA NT GEMM template: Out[m,n] = sum_k A[m,k]*B[n,k]
// 64x64 block tile, 4 waves (2x2), each wave 32x32 = 2x2 frags of 16x16x32.
// MODE 0: A=Ubf(bf16,lda=D)   B=Qtbf(ldb=D)   K=D    -> Sbf[c,q] (+bias)
// MODE 1: A=Q  (f32 ,lda=QL)  B=S1bf(ldb=QL)  K=QL   -> out rows [0,3D)
// MODE 2: A=C  (f32 ,lda=CL)  B=S2t (ldb=CL)  K=CL   -> Pbf[d,q]
// MODE 3: A=Pbf(bf16,lda=QL)  B=S1bf(ldb=QL)  K=QL   -> out rows [3D,4D)
// ---------------------------------------------------------------------------
template <int MODE, bool ABF16>
__global__ __launch_bounds__(256) void k_mfma_nt(const void* __restrict__ Av,
                                                 const unsigned short* __restrict__ Bm,
                                                 const float* __restrict__ bias,
                                                 const float* __restrict__ C,
                                                 unsigned short* __restrict__ Sbf,
                                                 float* __restrict__ out,
                                                 unsigned short* __restrict__ P) {
    constexpr int K = (MODE == 0) ? D_ : (MODE == 2 ? CL_ : QL_);
    constexpr int LDA = K;   // all operands are K-contiguous rows
    constexpr int LDB = K;
    constexpr size_t Astride = (MODE == 0) ? (size_t)CL_ * D_ : (size_t)D_ * K;
    constexpr size_t Bstride = (MODE == 0) ? (size_t)QL_ * D_
                             : (MODE == 2 ? (size_t)QL_ * CL_ : (size_t)CL_ * QL_);

    int b  = blockIdx.z;
    int n0 = blockIdx.x * 64;
    int m0 = blockIdx.y * 64;
    int tid  = threadIdx.x;
    int lane = tid & 63, wave = tid >> 6;
    int wm = wave >> 1, wn = wave & 1;
    int quad = lane >> 4, l15 = lane & 15;

    __shared__ __align__(16) short As[64][72];
    __shared__ __align__(16) short Bs[64][72];

    const unsigned short* Ab_bf = (const unsigned short*)Av + b * Astride + (size_t)m0 * LDA;
    const float*          Ab_f  = (const float*)Av          + b * Astride + (size_t)m0 * LDA;
    const unsigned short* Bb    = Bm + b * Bstride + (size_t)n0 * LDB;

    float4v acc[2][2] = {};

    for (int k0 = 0; k0 < K; k0 += 64) {
        // stage B (bf16)
        #pragma unroll
        for (int i = 0; i < 2; ++i) {
            int flat = tid + i * 256;
            int row = flat >> 3, col = (flat & 7) * 8;
            short8 v = *(const short8*)(Bb + (size_t)row * LDB + k0 + col);
            *(short8*)&Bs[row][col] = v;
        }
        // stage A
        if (ABF16) {
            #pragma unroll
            for (int i = 0; i < 2; ++i) {
                int flat = tid + i * 256;
                int row = flat >> 3, col = (flat & 7) * 8;
                short8 v = *(const short8*)(Ab_bf + (size_t)row * LDA + k0 + col);
                *(short8*)&As[row][col] = v;
            }
        } else {
            #pragma unroll
            for (int i = 0; i < 4; ++i) {
                int flat = tid + i * 256;
                int row = flat >> 4, col = (flat & 15) * 4;
                float4 a = *(const float4*)(Ab_f + (size_t)row * LDA + k0 + col);
                short4v p;
                p[0] = (short)f2bf(a.x); p[1] = (short)f2bf(a.y);
                p[2] = (short)f2bf(a.z); p[3] = (short)f2bf(a.w);
                *(short4v*)&As[row][col] = p;
            }
        }
        __syncthreads();
        #pragma unroll
        for (int ks = 0; ks < 64; ks += 32) {
            short8 af0 = *(const short8*)&As[wm * 32 + l15][ks + quad * 8];
            short8 af1 = *(const short8*)&As[wm * 32 + 16 + l15][ks + quad * 8];
            short8 bf0 = *(const short8*)&Bs[wn * 32 + l15][ks + quad * 8];
            short8 bf1 = *(const short8*)&Bs[wn * 32 + 16 + l15][ks + quad * 8];
            acc[0][0] = __builtin_amdgcn_mfma_f32_16x16x32_bf16(af0, bf0, acc[0][0], 0, 0, 0);
            acc[0][1] = __builtin_amdgcn_mfma_f32_16x16x32_bf16(af0, bf1, acc[0][1], 0, 0, 0);
            acc[1][0] = __builtin_amdgcn_mfma_f32_16x16x32_bf16(af1, bf0, acc[1][0], 0, 0, 0);
            acc[1][1] = __builtin_amdgcn_mfma_f32_16x16x32_bf16(af1, bf1, acc[1][1], 0, 0, 0);
        }
        __syncthreads();
    }

    #pragma unroll
    for (int fi = 0; fi < 2; ++fi)
        #pragma unroll
        for (int fj = 0; fj < 2; ++fj)
            #pragma unroll
            for (int r = 0; r < 4; ++r) {
                int m = m0 + wm * 32 + fi * 16 + quad * 4 + r;
                int n = n0 + wn * 32 + fj * 16 + l15;
                float v = acc[fi][fj][r];
                if (MODE == 0) {
                    v += bias[b * CL_ + m];
                    Sbf[((size_t)(b * CL_ + m)) * QL_ + n] = f2bf(v);
                } else if (MODE == 2) {
                    P[((size_t)(b * D_ + m)) * QL_ + n] = f2bf(v);
                } else {
                    float ct = C[((size_t)(b * D_ + m)) * CL_ + n];
                    if (MODE == 1) {
                        out[((size_t)(b * 4 * D_ + m)) * CL_ + n] = ct;
                        out[((size_t)(b * 4 * D_ + D_ + m)) * CL_ + n] = v;
                        out[((size_t)(b * 4 * D_ + 2 * D_ + m)) * CL_ + n] = ct * v;
                    } else {
                        out[((size_t)(b * 4 * D_ + 3 * D_ + m)) * CL_ + n] = ct * v;
                    }
                }
            }
}

// ---------------------------------------------------------------------------
// Kernel: fused stats. Each block owns a 64c x 512q tile of S.
// Phase 1: column partials — thread owns q=2*tid,2*tid+1; coalesced 4B/lane
//          loads down 64 rows; online (max,sum) -> pcmax/pcsum[b][chunk][q].
// Phase 2: row stats — same tile re-read (L2-hot), one row per wave iter,
//          shfl-reduce max then sum -> rmax/rinv.
// ---------------------------------------------------------------------------
__global__ __launch_bounds__(256) void k_stats(const unsigned short* __restrict__ S,
                                               float* __restrict__ rmax,
                                               float* __restrict__ rinv,
                                               float* __restrict__ pcmax,
                                               float* __restrict__ pcsum) {
    int b     = blockIdx.y;
    int chunk = blockIdx.x;      // 0..15
    int c0    = chunk * 64;
    int tid   = threadIdx.x;

    const unsigned short* Sb = S + (size_t)b * CL_ * QL_;

    // phase 1: column partials
    float m0 = -1e30f, s0 = 0.f, m1 = -1e30f, s1 = 0.f;
    #pragma unroll 4
    for (int c = 0; c < 64; ++c) {
        unsigned int raw = *(const unsigned int*)(Sb + (size_t)(c0 + c) * QL_ + 2 * tid);
        float v0 = bf2f((unsigned short)(raw & 0xFFFF));
        float v1 = bf2f((unsigned short)(raw >> 16));
        float nm0 = fmaxf(m0, v0);
        s0 = s0 * __expf(m0 - nm0) + __expf(v0 - nm0);
        m0 = nm0;
        float nm1 = fmaxf(m1, v1);
        s1 = s1 * __expf(m1 - nm1) + __expf(v1 - nm1);
        m1 = nm1;
    }
    size_t pbase = ((size_t)(b * 16 + chunk)) * QL_ + 2 * tid;
    *(float2*)(pcmax + pbase) = make_float2(m0, m1);
    *(float2*)(pcsum + pbase) = make_float2(s0, s1);

    // phase 2: row stats (L2-hot re-read); wave w handles rows w*16 .. w*16+15
    int lane = tid & 63, wave = tid >> 6;
    for (int i = 0; i < 16; ++i) {
        int c = c0 + wave * 16 + i;
        const unsigned short* Sr = Sb + (size_t)c * QL_ + lane * 8;
        uint4 raw = *(const uint4*)Sr;
        float v[8];
        v[0] = bf2f(raw.x & 0xFFFF); v[1] = bf2f(raw.x >> 16);
        v[2] = bf2f(raw.y & 0xFFFF); v[3] = bf2f(raw.y >> 16);
        v[4] = bf2f(raw.z & 0xFFFF); v[5] = bf2f(raw.z >> 16);
        v[6] = bf2f(raw.w & 0xFFFF); v[7] = bf2f(raw.w >> 16);
        float m = v[0];
        #pragma unroll
        for (int j = 1; j < 8; ++j) m = fmaxf(m, v[j]);
        for (int off = 32; off; off >>= 1) m = fmaxf(m, __shfl_xor(m, off));
        float s = 0.f;
        #pragma unroll
        for (int j = 0; j < 8; ++j) s += __expf(v[j] - m);
        for (int off = 32; off; off >>= 1) s += __shfl_xor(s, off);
        if (lane == 0) { rmax[b * CL_ + c] = m; rinv[b * CL_ + c] = 1.0f / s; }
    }
}

// ---------------------------------------------------------------------------
// Kernel: combine the 16 column partials per (b,q) -> cmax, cinv. Coalesced.
// ---------------------------------------------------------------------------
__global__ __launch_bounds__(256) void k_col_reduce(const float* __restrict__ pcmax,
                                                    const float* __restrict__ pcsum,
                                                    float* __restrict__ cmax,
                                                    float* __restrict__ cinv) {
    int g = blockIdx.x * 256 + threadIdx.x;   // 0 .. B*QL-1
    int b = g >> 9, q = g & (QL_ - 1);
    float M = -1e30f, SS = 0.f;
    #pragma unroll
    for (int ch = 0; ch < 16; ++ch) {
        size_t idx = ((size_t)(b * 16 + ch)) * QL_ + q;
        float m = pcmax[idx], s = pcsum[idx];
        float nM = fmaxf(M, m);
        SS = SS * __expf(M - nM) + s * __expf(m - nM);
        M = nM;
    }
    cmax[g] = M;
    cinv[g] = 1.0f / SS;
}

// ---------------------------------------------------------------------------
// Kernel: normalize — S1bf[c,q] = exp(s-rmax[c])*rinv[c];
//                     S2t[q,c] = exp(s-cmax[q])*cinv[q]  (LDS transpose)
// ---------------------------------------------------------------------------
__global__ __launch_bounds__(256) void k_normalize(const unsigned short* __restrict__ S,
                                                   const float* __restrict__ rmax,
                                                   const float* __restrict__ rinv,
                                                   const float* __restrict__ cmax,
                                                   const float* __restrict__ cinv,
                                                   unsigned short* __restrict__ S1,
                                                   unsigned short* __restrict__ S2t) {
    int b  = blockIdx.z;
    int c0 = blockIdx.y * 64;
    int q0 = blockIdx.x * 64;
    int tid = threadIdx.x;

    __shared__ __align__(16) short t[64][72];   // [c][q] of s2 (bf16 bits)
    __shared__ float scm[64], sci[64], srm[64], sri[64];

    if (tid < 64) {
        scm[tid] = cmax[b * QL_ + q0 + tid];
        sci[tid] = cinv[b * QL_ + q0 + tid];
        srm[tid] = rmax[b * CL_ + c0 + tid];
        sri[tid] = rinv[b * CL_ + c0 + tid];
    }
    __syncthreads();

    // phase 1: read S, write S1 (coalesced), stage s2 in LDS
    #pragma unroll
    for (int p = 0; p < 2; ++p) {
        int c  = p * 32 + (tid >> 3);
        int qb = (tid & 7) * 8;
        const unsigned short* Sp = S + ((size_t)(b * CL_ + c0 + c)) * QL_ + q0 + qb;
        uint4 raw = *(const uint4*)Sp;
        unsigned int rw[4] = {raw.x, raw.y, raw.z, raw.w};
        float rm = srm[c], ri = sri[c];
        short8 s1v, s2v;
        #pragma unroll
        for (int j = 0; j < 8; ++j) {
            unsigned short bits = (unsigned short)((rw[j >> 1] >> ((j & 1) * 16)) & 0xFFFF);
            float sv = bf2f(bits);
            s1v[j] = (short)f2bf(__expf(sv - rm) * ri);
            s2v[j] = (short)f2bf(__expf(sv - scm[qb + j]) * sci[qb + j]);
        }
        *(short8*)(S1 + ((size_t)(b * CL_ + c0 + c)) * QL_ + q0 + qb) = s1v;
        *(short8*)&t[c][qb] = s2v;
    }
    __syncthreads();
    // phase 2: write S2t transposed, lanes over c (coalesced)
    #pragma unroll
    for (int p = 0; p < 16; ++p) {
        int q = p * 4 + (tid >> 6);
        int c = tid & 63;
        S2t[((size_t)(b * QL_ + q0 + q)) * CL_ + c0 + c] = (unsigned short)t[c][q];
    }
}

// ---------------------------------------------------------------------------
// Launch. Workspace:
//   slotA (33.6 MB): Ubf [steps 1-3]  then S2t [steps 6-8]
//   slotB ( 4.2 MB): Qtbf [2-3]       then Pbf [8-9]
//   S1bf  (33.6 MB)
//   bias/rmax/rinv/cmax/cinv (~0.5 MB) + pcmax/pcsum (2 MB)
// Sbf (33.6 MB, bf16) lives in d_out (dead until MODE-1 writes out).  ~74 MB.
// ---------------------------------------------------------------------------
extern "C" void kernel_launch(void* const* d_in, const int* in_sizes, int n_in,
                              void* d_out, int out_size, void* d_ws, size_t ws_size,
                              hipStream_t stream) {
    const float* C = (const float*)d_in[0];
    const float* Q = (const float*)d_in[1];
    const float* W = (const float*)d_in[2];
    float* out = (float*)d_out;

    char* ws = (char*)d_ws;
    unsigned short* slotA = (unsigned short*)ws;                 // Ubf / S2t
    size_t slotA_elems = (size_t)B_ * CL_ * QL_;
    unsigned short* slotB = slotA + slotA_elems;                 // Qtbf / Pbf
    size_t slotB_elems = (size_t)B_ * QL_ * D_;
    unsigned short* S1bf = slotB + slotB_elems;
    size_t s1_elems = (size_t)B_ * CL_ * QL_;
    float* bias  = (float*)(S1bf + s1_elems);
    float* rmax  = bias + (size_t)B_ * CL_;
    float* rinv  = rmax + (size_t)B_ * CL_;
    float* cmax  = rinv + (size_t)B_ * CL_;
    float* cinv  = cmax + (size_t)B_ * QL_;
    float* pcmax = cinv + (size_t)B_ * QL_;
    float* pcsum = pcmax + (size_t)B_ * 16 * QL_;

    unsigned short* Ubf  = slotA;
    unsigned short* S2t  = slotA;
    unsigned short* Qtbf = slotB;
    unsigned short* Pbf  = slotB;
    unsigned short* Sbf  = (unsigned short*)d_out;   // dead until MODE-1 writes out

    k_u_bias<<<dim3(CL_ / 32, B_), 256, 0, stream>>>(C, W, Ubf, bias);
    k_qt<<<dim3(QL_ / 64, D_ / 64, B_), 256, 0, stream>>>(Q, Qtbf);
    k_mfma_nt<0, true><<<dim3(QL_ / 64, CL_ / 64, B_), 256, 0, stream>>>(
        Ubf, Qtbf, bias, C, Sbf, out, Pbf);
    k_stats<<<dim3(16, B_), 256, 0, stream>>>(Sbf, rmax, rinv, pcmax, pcsum);
    k_col_reduce<<<B_ * QL_ / 256, 256, 0, stream>>>(pcmax, pcsum, cmax, cinv);
    k_normalize<<<dim3(QL_ / 64, CL_ / 64, B_), 256, 0, stream>>>(
        Sbf, rmax, rinv, cmax, cinv, S1bf, S2t);
    k_mfma_nt<1, false><<<dim3(CL_ / 64, D_ / 64, B_), 256, 0, stream>>>(
        Q, S1bf, bias, C, Sbf, out, Pbf);
    k_mfma_nt<2, false><<<dim3(QL_ / 64, D_ / 64, B_), 256, 0, stream>>>(
        C, S2t, bias, C, Sbf, out, Pbf);
    k_mfma_nt<3, true><<<dim3(CL_ / 64, D_ / 64, B_), 256, 0, stream>>>(
        Pbf, S1bf, bias, C, Sbf, out, Pbf);
}

// Round 5
// 228.839 us; speedup vs baseline: 2.0836x; 1.2080x over previous
//
#include <hip/hip_runtime.h>
#include <hip/hip_bf16.h>
#include <cstddef>

// Problem constants (B, D, CL, QL) = (32, 128, 1024, 512)
#define B_  32
#define D_  128
#define CL_ 1024
#define QL_ 512

using short8  = __attribute__((ext_vector_type(8))) short;
using short4v = __attribute__((ext_vector_type(4))) short;
using float4v = __attribute__((ext_vector_type(4))) float;

__device__ __forceinline__ unsigned short f2bf(float f) {
    unsigned int u = __float_as_uint(f);
    u += 0x7FFFu + ((u >> 16) & 1u);   // RTNE
    return (unsigned short)(u >> 16);
}
__device__ __forceinline__ float bf2f(unsigned short h) {
    return __uint_as_float(((unsigned int)h) << 16);
}

// ---------------------------------------------------------------------------
// Kernel 1: Ubf[c,d] = bf16(wq + wqc*Ct); bias[c] = sum_d wc*Ct;
//           Cbf[b,d,c] = bf16(C).  W read as float4 (128B segments/row).
// ---------------------------------------------------------------------------
__global__ __launch_bounds__(256) void k_u_bias(const float* __restrict__ C,
                                                const float* __restrict__ W,
                                                unsigned short* __restrict__ U,
                                                float* __restrict__ bias,
                                                unsigned short* __restrict__ Cbf) {
    int b  = blockIdx.y;
    int c0 = blockIdx.x * 32;
    int tid = threadIdx.x;

    __shared__ float tile[128][33];
    __shared__ float bred[32][9];

    for (int pass = 0; pass < 16; ++pass) {
        int d = pass * 8 + (tid >> 5);
        int c = tid & 31;
        float v = C[((size_t)(b * D_ + d)) * CL_ + c0 + c];
        tile[d][c] = v;
        Cbf[((size_t)(b * D_ + d)) * CL_ + c0 + c] = f2bf(v);
    }
    __syncthreads();

    int tc    = tid >> 3;
    int lane8 = tid & 7;
    int c     = c0 + tc;
    size_t wbase = ((size_t)(b * CL_ + c)) * (3 * D_);
    size_t ubase = ((size_t)(b * CL_ + c)) * D_;

    float bpart = 0.f;
    #pragma unroll
    for (int i = 0; i < 4; ++i) {
        int d = i * 32 + lane8 * 4;
        float4 wq4  = *(const float4*)(W + wbase + d);
        float4 wc4  = *(const float4*)(W + wbase + D_ + d);
        float4 wqc4 = *(const float4*)(W + wbase + 2 * D_ + d);
        float ct0 = tile[d + 0][tc], ct1 = tile[d + 1][tc];
        float ct2 = tile[d + 2][tc], ct3 = tile[d + 3][tc];
        short4v u;
        u[0] = (short)f2bf(wq4.x + wqc4.x * ct0);
        u[1] = (short)f2bf(wq4.y + wqc4.y * ct1);
        u[2] = (short)f2bf(wq4.z + wqc4.z * ct2);
        u[3] = (short)f2bf(wq4.w + wqc4.w * ct3);
        *(short4v*)(U + ubase + d) = u;
        bpart += wc4.x * ct0 + wc4.y * ct1 + wc4.z * ct2 + wc4.w * ct3;
    }
    bred[tc][lane8] = bpart;
    __syncthreads();
    if (lane8 == 0) {
        float s = 0.f;
        for (int i = 0; i < 8; ++i) s += bred[tc][i];
        bias[b * CL_ + c] = s;
    }
}

// ---------------------------------------------------------------------------
// Kernel 2: Qtbf[b,q,d] = bf16(Q[b,d,q]) (LDS transpose); Qbf[b,d,q] = bf16(Q).
// ---------------------------------------------------------------------------
__global__ __launch_bounds__(256) void k_qt(const float* __restrict__ Q,
                                            unsigned short* __restrict__ Qt,
                                            unsigned short* __restrict__ Qbf) {
    int b  = blockIdx.z;
    int d0 = blockIdx.y * 64;
    int q0 = blockIdx.x * 64;
    int tid = threadIdx.x;
    __shared__ float t[64][65];
    for (int p = 0; p < 16; ++p) {
        int d = p * 4 + (tid >> 6);
        int q = tid & 63;
        float v = Q[((size_t)(b * D_ + d0 + d)) * QL_ + q0 + q];
        t[d][q] = v;
        Qbf[((size_t)(b * D_ + d0 + d)) * QL_ + q0 + q] = f2bf(v);
    }
    __syncthreads();
    for (int p = 0; p < 16; ++p) {
        int q  = p * 4 + (tid >> 6);
        int dd = tid & 63;
        Qt[((size_t)(b * QL_ + q0 + q)) * D_ + d0 + dd] = f2bf(t[dd][q]);
    }
}

// ---------------------------------------------------------------------------
// G_S: Sbf[c,q] = Ubf[c,:]·Qtbf[q,:] + bias[c].  64x64 tile, K=128.
// Plain dim3 grid (proven R3 geometry; no XCD swizzle).
// ---------------------------------------------------------------------------
__global__ __launch_bounds__(256) void k_gs(const unsigned short* __restrict__ Ubf,
                                            const unsigned short* __restrict__ Qtbf,
                                            const float* __restrict__ bias,
                                            unsigned short* __restrict__ Sbf) {
    int b  = blockIdx.z;
    int m0 = blockIdx.y * 64;
    int n0 = blockIdx.x * 64;

    int tid  = threadIdx.x;
    int lane = tid & 63, wave = tid >> 6;
    int wm = wave >> 1, wn = wave & 1;
    int quad = lane >> 4, l15 = lane & 15;

    __shared__ __align__(16) short As[64][72];
    __shared__ __align__(16) short Bs[64][72];

    const unsigned short* Ab = Ubf  + ((size_t)(b * CL_ + m0)) * D_;
    const unsigned short* Bb = Qtbf + ((size_t)(b * QL_ + n0)) * D_;

    float4v acc[2][2] = {};

    for (int k0 = 0; k0 < D_; k0 += 64) {
        #pragma unroll
        for (int i = 0; i < 2; ++i) {
            int flat = tid + i * 256;
            int row = flat >> 3, col = (flat & 7) * 8;
            *(short8*)&As[row][col] = *(const short8*)(Ab + (size_t)row * D_ + k0 + col);
            *(short8*)&Bs[row][col] = *(const short8*)(Bb + (size_t)row * D_ + k0 + col);
        }
        __syncthreads();
        #pragma unroll
        for (int ks = 0; ks < 64; ks += 32) {
            short8 af0 = *(const short8*)&As[wm * 32 + l15][ks + quad * 8];
            short8 af1 = *(const short8*)&As[wm * 32 + 16 + l15][ks + quad * 8];
            short8 bf0 = *(const short8*)&Bs[wn * 32 + l15][ks + quad * 8];
            short8 bf1 = *(const short8*)&Bs[wn * 32 + 16 + l15][ks + quad * 8];
            acc[0][0] = __builtin_amdgcn_mfma_f32_16x16x32_bf16(af0, bf0, acc[0][0], 0, 0, 0);
            acc[0][1] = __builtin_amdgcn_mfma_f32_16x16x32_bf16(af0, bf1, acc[0][1], 0, 0, 0);
            acc[1][0] = __builtin_amdgcn_mfma_f32_16x16x32_bf16(af1, bf0, acc[1][0], 0, 0, 0);
            acc[1][1] = __builtin_amdgcn_mfma_f32_16x16x32_bf16(af1, bf1, acc[1][1], 0, 0, 0);
        }
        __syncthreads();
    }

    #pragma unroll
    for (int fi = 0; fi < 2; ++fi)
        #pragma unroll
        for (int fj = 0; fj < 2; ++fj)
            #pragma unroll
            for (int rr = 0; rr < 4; ++rr) {
                int m = m0 + wm * 32 + fi * 16 + quad * 4 + rr;
                int nn = n0 + wn * 32 + fj * 16 + l15;
                float v = acc[fi][fj][rr] + bias[b * CL_ + m];
                Sbf[((size_t)(b * CL_ + m)) * QL_ + nn] = f2bf(v);
            }
}

// ---------------------------------------------------------------------------
// Fused stats (proven in R3).
// ---------------------------------------------------------------------------
__global__ __launch_bounds__(256) void k_stats(const unsigned short* __restrict__ S,
                                               float* __restrict__ rmax,
                                               float* __restrict__ rinv,
                                               float* __restrict__ pcmax,
                                               float* __restrict__ pcsum) {
    int b     = blockIdx.y;
    int chunk = blockIdx.x;      // 0..15
    int c0    = chunk * 64;
    int tid   = threadIdx.x;

    const unsigned short* Sb = S + (size_t)b * CL_ * QL_;

    float m0 = -1e30f, s0 = 0.f, m1 = -1e30f, s1 = 0.f;
    #pragma unroll 4
    for (int c = 0; c < 64; ++c) {
        unsigned int raw = *(const unsigned int*)(Sb + (size_t)(c0 + c) * QL_ + 2 * tid);
        float v0 = bf2f((unsigned short)(raw & 0xFFFF));
        float v1 = bf2f((unsigned short)(raw >> 16));
        float nm0 = fmaxf(m0, v0);
        s0 = s0 * __expf(m0 - nm0) + __expf(v0 - nm0);
        m0 = nm0;
        float nm1 = fmaxf(m1, v1);
        s1 = s1 * __expf(m1 - nm1) + __expf(v1 - nm1);
        m1 = nm1;
    }
    size_t pbase = ((size_t)(b * 16 + chunk)) * QL_ + 2 * tid;
    *(float2*)(pcmax + pbase) = make_float2(m0, m1);
    *(float2*)(pcsum + pbase) = make_float2(s0, s1);

    int lane = tid & 63, wave = tid >> 6;
    for (int i = 0; i < 16; ++i) {
        int c = c0 + wave * 16 + i;
        const unsigned short* Sr = Sb + (size_t)c * QL_ + lane * 8;
        uint4 raw = *(const uint4*)Sr;
        float v[8];
        v[0] = bf2f(raw.x & 0xFFFF); v[1] = bf2f(raw.x >> 16);
        v[2] = bf2f(raw.y & 0xFFFF); v[3] = bf2f(raw.y >> 16);
        v[4] = bf2f(raw.z & 0xFFFF); v[5] = bf2f(raw.z >> 16);
        v[6] = bf2f(raw.w & 0xFFFF); v[7] = bf2f(raw.w >> 16);
        float m = v[0];
        #pragma unroll
        for (int j = 1; j < 8; ++j) m = fmaxf(m, v[j]);
        for (int off = 32; off; off >>= 1) m = fmaxf(m, __shfl_xor(m, off));
        float s = 0.f;
        #pragma unroll
        for (int j = 0; j < 8; ++j) s += __expf(v[j] - m);
        for (int off = 32; off; off >>= 1) s += __shfl_xor(s, off);
        if (lane == 0) { rmax[b * CL_ + c] = m; rinv[b * CL_ + c] = 1.0f / s; }
    }
}

__global__ __launch_bounds__(256) void k_col_reduce(const float* __restrict__ pcmax,
                                                    const float* __restrict__ pcsum,
                                                    float* __restrict__ cmax,
                                                    float* __restrict__ cinv) {
    int g = blockIdx.x * 256 + threadIdx.x;
    int b = g >> 9, q = g & (QL_ - 1);
    float M = -1e30f, SS = 0.f;
    #pragma unroll
    for (int ch = 0; ch < 16; ++ch) {
        size_t idx = ((size_t)(b * 16 + ch)) * QL_ + q;
        float m = pcmax[idx], s = pcsum[idx];
        float nM = fmaxf(M, m);
        SS = SS * __expf(M - nM) + s * __expf(m - nM);
        M = nM;
    }
    cmax[g] = M;
    cinv[g] = 1.0f / SS;
}

// ---------------------------------------------------------------------------
// G_P: Pbf[d,q] = sum_c Cbf[d,c] * S2[c,q], S2 on-the-fly (exp + LDS transpose).
// Tile M=128 x N=32 q, K=CL, BK=64.  Plain dim3 grid (no swizzle).
// ---------------------------------------------------------------------------
__global__ __launch_bounds__(256) void k_gp(const unsigned short* __restrict__ Cbf,
                                            const unsigned short* __restrict__ Sbf,
                                            const float* __restrict__ cmax,
                                            const float* __restrict__ cinv,
                                            unsigned short* __restrict__ Pbf) {
    int b  = blockIdx.y;
    int q0 = blockIdx.x * 32;

    int tid  = threadIdx.x;
    int lane = tid & 63, wave = tid >> 6;   // wave owns m-range wave*32
    int quad = lane >> 4, l15 = lane & 15;

    __shared__ __align__(16) short As[128][72];
    __shared__ __align__(16) short Bs[32][72];
    __shared__ float scm[32], sci[32];

    if (tid < 32) {
        scm[tid] = cmax[b * QL_ + q0 + tid];
        sci[tid] = cinv[b * QL_ + q0 + tid];
    }
    __syncthreads();

    const unsigned short* Cb = Cbf + (size_t)b * D_ * CL_;
    const unsigned short* Sb = Sbf + (size_t)b * CL_ * QL_;

    int arow = tid >> 3;          // 0..31
    int acol = (tid & 7) * 8;
    int srow = tid >> 4;          // 0..15
    int uq   = tid & 15;          // uint index over q (2 q each)

    float4v acc[2][2] = {};

    for (int k0 = 0; k0 < CL_; k0 += 64) {
        #pragma unroll
        for (int p = 0; p < 4; ++p) {
            int row = p * 32 + arow;
            *(short8*)&As[row][acol] = *(const short8*)(Cb + (size_t)row * CL_ + k0 + acol);
        }
        #pragma unroll
        for (int p = 0; p < 4; ++p) {
            int crow = p * 16 + srow;
            unsigned int raw = *(const unsigned int*)(Sb + (size_t)(k0 + crow) * QL_ + q0 + 2 * uq);
            float v0 = __expf(bf2f((unsigned short)(raw & 0xFFFF)) - scm[2 * uq]) * sci[2 * uq];
            float v1 = __expf(bf2f((unsigned short)(raw >> 16)) - scm[2 * uq + 1]) * sci[2 * uq + 1];
            Bs[2 * uq][crow]     = (short)f2bf(v0);
            Bs[2 * uq + 1][crow] = (short)f2bf(v1);
        }
        __syncthreads();
        #pragma unroll
        for (int ks = 0; ks < 64; ks += 32) {
            short8 a0 = *(const short8*)&As[wave * 32 + l15][ks + quad * 8];
            short8 a1 = *(const short8*)&As[wave * 32 + 16 + l15][ks + quad * 8];
            short8 b0 = *(const short8*)&Bs[l15][ks + quad * 8];
            short8 b1 = *(const short8*)&Bs[16 + l15][ks + quad * 8];
            acc[0][0] = __builtin_amdgcn_mfma_f32_16x16x32_bf16(a0, b0, acc[0][0], 0, 0, 0);
            acc[0][1] = __builtin_amdgcn_mfma_f32_16x16x32_bf16(a0, b1, acc[0][1], 0, 0, 0);
            acc[1][0] = __builtin_amdgcn_mfma_f32_16x16x32_bf16(a1, b0, acc[1][0], 0, 0, 0);
            acc[1][1] = __builtin_amdgcn_mfma_f32_16x16x32_bf16(a1, b1, acc[1][1], 0, 0, 0);
        }
        __syncthreads();
    }

    #pragma unroll
    for (int fi = 0; fi < 2; ++fi)
        #pragma unroll
        for (int fj = 0; fj < 2; ++fj)
            #pragma unroll
            for (int rr = 0; rr < 4; ++rr) {
                int d = wave * 32 + fi * 16 + quad * 4 + rr;
                int q = q0 + fj * 16 + l15;
                Pbf[((size_t)(b * D_ + d)) * QL_ + q] = f2bf(acc[fi][fj][rr]);
            }
}

// ---------------------------------------------------------------------------
// k_av<PLANE>: Out[d,c] = sum_q A[d,q]*S1[c,q], S1 on-the-fly from Sbf+stats.
// PLANE 0 (A=Qbf): writes out planes 0 (Ct), 1 (At), 2 (Ct*At).
// PLANE 1 (A=Pbf): writes out plane 3 (Ct*Bmt).
// Tile M=128 x N=32 c, K=QL, BK=64.  Plain dim3 grid.
// ---------------------------------------------------------------------------
template <int PLANE>
__global__ __launch_bounds__(256) void k_av(const unsigned short* __restrict__ A,
                                            const unsigned short* __restrict__ Sbf,
                                            const float* __restrict__ rmax,
                                            const float* __restrict__ rinv,
                                            const float* __restrict__ C,
                                            float* __restrict__ out) {
    int b  = blockIdx.y;
    int n0 = blockIdx.x * 32;   // c range

    int tid  = threadIdx.x;
    int lane = tid & 63, wave = tid >> 6;
    int quad = lane >> 4, l15 = lane & 15;

    __shared__ __align__(16) short As[128][72];
    __shared__ __align__(16) short Bs[32][72];
    __shared__ float srm[32], sri[32];

    if (tid < 32) {
        srm[tid] = rmax[b * CL_ + n0 + tid];
        sri[tid] = rinv[b * CL_ + n0 + tid];
    }
    __syncthreads();

    const unsigned short* Ab = A + (size_t)b * D_ * QL_;
    const unsigned short* Sb = Sbf + ((size_t)(b * CL_ + n0)) * QL_;

    int arow = tid >> 3;          // 0..31
    int acol = (tid & 7) * 8;

    float4v acc[2][2] = {};

    for (int k0 = 0; k0 < QL_; k0 += 64) {
        #pragma unroll
        for (int p = 0; p < 4; ++p) {
            int row = p * 32 + arow;
            *(short8*)&As[row][acol] = *(const short8*)(Ab + (size_t)row * QL_ + k0 + acol);
        }
        {
            int brow = tid >> 3;  // 0..31 (c local)
            uint4 raw = *(const uint4*)(Sb + (size_t)brow * QL_ + k0 + acol);
            unsigned int rw[4] = {raw.x, raw.y, raw.z, raw.w};
            float rm = srm[brow], ri = sri[brow];
            short8 v;
            #pragma unroll
            for (int j = 0; j < 8; ++j) {
                unsigned short bits = (unsigned short)((rw[j >> 1] >> ((j & 1) * 16)) & 0xFFFF);
                v[j] = (short)f2bf(__expf(bf2f(bits) - rm) * ri);
            }
            *(short8*)&Bs[brow][acol] = v;
        }
        __syncthreads();
        #pragma unroll
        for (int ks = 0; ks < 64; ks += 32) {
            short8 a0 = *(const short8*)&As[wave * 32 + l15][ks + quad * 8];
            short8 a1 = *(const short8*)&As[wave * 32 + 16 + l15][ks + quad * 8];
            short8 b0 = *(const short8*)&Bs[l15][ks + quad * 8];
            short8 b1 = *(const short8*)&Bs[16 + l15][ks + quad * 8];
            acc[0][0] = __builtin_amdgcn_mfma_f32_16x16x32_bf16(a0, b0, acc[0][0], 0, 0, 0);
            acc[0][1] = __builtin_amdgcn_mfma_f32_16x16x32_bf16(a0, b1, acc[0][1], 0, 0, 0);
            acc[1][0] = __builtin_amdgcn_mfma_f32_16x16x32_bf16(a1, b0, acc[1][0], 0, 0, 0);
            acc[1][1] = __builtin_amdgcn_mfma_f32_16x16x32_bf16(a1, b1, acc[1][1], 0, 0, 0);
        }
        __syncthreads();
    }

    #pragma unroll
    for (int fi = 0; fi < 2; ++fi)
        #pragma unroll
        for (int fj = 0; fj < 2; ++fj)
            #pragma unroll
            for (int rr = 0; rr < 4; ++rr) {
                int d = wave * 32 + fi * 16 + quad * 4 + rr;
                int c = n0 + fj * 16 + l15;
                float ct = C[((size_t)(b * D_ + d)) * CL_ + c];
                float v  = acc[fi][fj][rr];
                size_t ob = ((size_t)(b * 4 * D_ + d)) * CL_ + c;
                if (PLANE == 0) {
                    out[ob]                        = ct;
                    out[ob + (size_t)D_ * CL_]     = v;
                    out[ob + 2 * (size_t)D_ * CL_] = ct * v;
                } else {
                    out[ob + 3 * (size_t)D_ * CL_] = ct * v;
                }
            }
}

// ---------------------------------------------------------------------------
// Launch. Workspace (~62.5 MB): Ubf 8.4, Qtbf 4.2, Qbf 4.2, Cbf 8.4, Pbf 4.2,
// Sbf 33.6, stats ~2.6 MB.
// ---------------------------------------------------------------------------
extern "C" void kernel_launch(void* const* d_in, const int* in_sizes, int n_in,
                              void* d_out, int out_size, void* d_ws, size_t ws_size,
                              hipStream_t stream) {
    const float* C = (const float*)d_in[0];
    const float* Q = (const float*)d_in[1];
    const float* W = (const float*)d_in[2];
    float* out = (float*)d_out;

    unsigned short* Ubf  = (unsigned short*)d_ws;
    unsigned short* Qtbf = Ubf  + (size_t)B_ * CL_ * D_;
    unsigned short* Qbf  = Qtbf + (size_t)B_ * QL_ * D_;
    unsigned short* Cbf  = Qbf  + (size_t)B_ * D_ * QL_;
    unsigned short* Pbf  = Cbf  + (size_t)B_ * D_ * CL_;
    unsigned short* Sbf  = Pbf  + (size_t)B_ * D_ * QL_;
    float* bias  = (float*)(Sbf + (size_t)B_ * CL_ * QL_);
    float* rmax  = bias  + (size_t)B_ * CL_;
    float* rinv  = rmax  + (size_t)B_ * CL_;
    float* cmax  = rinv  + (size_t)B_ * CL_;
    float* cinv  = cmax  + (size_t)B_ * QL_;
    float* pcmax = cinv  + (size_t)B_ * QL_;
    float* pcsum = pcmax + (size_t)B_ * 16 * QL_;

    k_u_bias<<<dim3(CL_ / 32, B_), 256, 0, stream>>>(C, W, Ubf, bias, Cbf);
    k_qt<<<dim3(QL_ / 64, D_ / 64, B_), 256, 0, stream>>>(Q, Qtbf, Qbf);
    k_gs<<<dim3(QL_ / 64, CL_ / 64, B_), 256, 0, stream>>>(Ubf, Qtbf, bias, Sbf);
    k_stats<<<dim3(16, B_), 256, 0, stream>>>(Sbf, rmax, rinv, pcmax, pcsum);
    k_col_reduce<<<B_ * QL_ / 256, 256, 0, stream>>>(pcmax, pcsum, cmax, cinv);
    k_gp<<<dim3(QL_ / 32, B_), 256, 0, stream>>>(Cbf, Sbf, cmax, cinv, Pbf);
    k_av<0><<<dim3(CL_ / 32, B_), 256, 0, stream>>>(Qbf, Sbf, rmax, rinv, C, out);
    k_av<1><<<dim3(CL_ / 32, B_), 256, 0, stream>>>(Pbf, Sbf, rmax, rinv, C, out);
}

// Round 6
// 205.432 us; speedup vs baseline: 2.3210x; 1.1139x over previous
//
#include <hip/hip_runtime.h>
#include <hip/hip_bf16.h>
#include <cstddef>

// Problem constants (B, D, CL, QL) = (32, 128, 1024, 512)
#define B_  32
#define D_  128
#define CL_ 1024
#define QL_ 512

using short8  = __attribute__((ext_vector_type(8))) short;
using short4v = __attribute__((ext_vector_type(4))) short;
using float4v = __attribute__((ext_vector_type(4))) float;

__device__ __forceinline__ unsigned short f2bf(float f) {
    unsigned int u = __float_as_uint(f);
    u += 0x7FFFu + ((u >> 16) & 1u);   // RTNE
    return (unsigned short)(u >> 16);
}
__device__ __forceinline__ float bf2f(unsigned short h) {
    return __uint_as_float(((unsigned int)h) << 16);
}

// ---------------------------------------------------------------------------
// Kernel 1: Ubf[c,d] = bf16(wq + wqc*Ct); bias[c] = sum_d wc*Ct;
//           Cbf[b,d,c] = bf16(C).  W read as float4 (128B segments/row).
// ---------------------------------------------------------------------------
__global__ __launch_bounds__(256) void k_u_bias(const float* __restrict__ C,
                                                const float* __restrict__ W,
                                                unsigned short* __restrict__ U,
                                                float* __restrict__ bias,
                                                unsigned short* __restrict__ Cbf) {
    int b  = blockIdx.y;
    int c0 = blockIdx.x * 32;
    int tid = threadIdx.x;

    __shared__ float tile[128][33];
    __shared__ float bred[32][9];

    for (int pass = 0; pass < 16; ++pass) {
        int d = pass * 8 + (tid >> 5);
        int c = tid & 31;
        float v = C[((size_t)(b * D_ + d)) * CL_ + c0 + c];
        tile[d][c] = v;
        Cbf[((size_t)(b * D_ + d)) * CL_ + c0 + c] = f2bf(v);
    }
    __syncthreads();

    int tc    = tid >> 3;
    int lane8 = tid & 7;
    int c     = c0 + tc;
    size_t wbase = ((size_t)(b * CL_ + c)) * (3 * D_);
    size_t ubase = ((size_t)(b * CL_ + c)) * D_;

    float bpart = 0.f;
    #pragma unroll
    for (int i = 0; i < 4; ++i) {
        int d = i * 32 + lane8 * 4;
        float4 wq4  = *(const float4*)(W + wbase + d);
        float4 wc4  = *(const float4*)(W + wbase + D_ + d);
        float4 wqc4 = *(const float4*)(W + wbase + 2 * D_ + d);
        float ct0 = tile[d + 0][tc], ct1 = tile[d + 1][tc];
        float ct2 = tile[d + 2][tc], ct3 = tile[d + 3][tc];
        short4v u;
        u[0] = (short)f2bf(wq4.x + wqc4.x * ct0);
        u[1] = (short)f2bf(wq4.y + wqc4.y * ct1);
        u[2] = (short)f2bf(wq4.z + wqc4.z * ct2);
        u[3] = (short)f2bf(wq4.w + wqc4.w * ct3);
        *(short4v*)(U + ubase + d) = u;
        bpart += wc4.x * ct0 + wc4.y * ct1 + wc4.z * ct2 + wc4.w * ct3;
    }
    bred[tc][lane8] = bpart;
    __syncthreads();
    if (lane8 == 0) {
        float s = 0.f;
        for (int i = 0; i < 8; ++i) s += bred[tc][i];
        bias[b * CL_ + c] = s;
    }
}

// ---------------------------------------------------------------------------
// Kernel 2: Qtbf[b,q,d] = bf16(Q[b,d,q]) (LDS transpose); Qbf[b,d,q] = bf16(Q).
// ---------------------------------------------------------------------------
__global__ __launch_bounds__(256) void k_qt(const float* __restrict__ Q,
                                            unsigned short* __restrict__ Qt,
                                            unsigned short* __restrict__ Qbf) {
    int b  = blockIdx.z;
    int d0 = blockIdx.y * 64;
    int q0 = blockIdx.x * 64;
    int tid = threadIdx.x;
    __shared__ float t[64][65];
    for (int p = 0; p < 16; ++p) {
        int d = p * 4 + (tid >> 6);
        int q = tid & 63;
        float v = Q[((size_t)(b * D_ + d0 + d)) * QL_ + q0 + q];
        t[d][q] = v;
        Qbf[((size_t)(b * D_ + d0 + d)) * QL_ + q0 + q] = f2bf(v);
    }
    __syncthreads();
    for (int p = 0; p < 16; ++p) {
        int q  = p * 4 + (tid >> 6);
        int dd = tid & 63;
        Qt[((size_t)(b * QL_ + q0 + q)) * D_ + d0 + dd] = f2bf(t[dd][q]);
    }
}

// ---------------------------------------------------------------------------
// k_gs2: fused S GEMM + softmax stats.
// Block = (b, mt): 64 c-rows x all 512 q, K=128, 8 n-chunks of 64.
//   - Sbf[c,q] = Ubf[c,:]·Qtbf[q,:] + bias[c]   (written per chunk)
//   - row stats (over q): online in registers across chunks -> rmax/rinv
//   - column partials (over this block's 64 c) per chunk -> pcmax/pcsum
// ---------------------------------------------------------------------------
__global__ __launch_bounds__(256) void k_gs2(const unsigned short* __restrict__ Ubf,
                                             const unsigned short* __restrict__ Qtbf,
                                             const float* __restrict__ bias,
                                             unsigned short* __restrict__ Sbf,
                                             float* __restrict__ rmax,
                                             float* __restrict__ rinv,
                                             float* __restrict__ pcmax,
                                             float* __restrict__ pcsum) {
    int mt = blockIdx.x;          // 0..15 (c-chunk of 64)
    int b  = blockIdx.y;
    int m0 = mt * 64;
    int tid  = threadIdx.x;
    int lane = tid & 63, wave = tid >> 6;
    int wm = wave >> 1, wn = wave & 1;
    int quad = lane >> 4, l15 = lane & 15;

    __shared__ __align__(16) short As[64][136];   // 64 c x 128 k
    __shared__ __align__(16) short Bs[64][136];   // 64 q x 128 k (per chunk)
    __shared__ float sbias[64];
    __shared__ float rmw[2][64], rsw[2][64];      // [wn][row]
    __shared__ float cmw[2][64], csw[2][64];      // [wm][col]

    const unsigned short* Ab = Ubf  + ((size_t)(b * CL_ + m0)) * D_;
    const unsigned short* Bb = Qtbf + ((size_t)(b * QL_)) * D_;

    // stage A once (whole K)
    #pragma unroll
    for (int i = 0; i < 4; ++i) {
        int flat = tid + i * 256;
        int row = flat >> 4, col = (flat & 15) * 8;
        *(short8*)&As[row][col] = *(const short8*)(Ab + (size_t)row * D_ + col);
    }
    if (tid < 64) sbias[tid] = bias[b * CL_ + m0 + tid];

    float rm_run[2][4], rs_run[2][4];
    #pragma unroll
    for (int fi = 0; fi < 2; ++fi)
        #pragma unroll
        for (int rr = 0; rr < 4; ++rr) { rm_run[fi][rr] = -1e30f; rs_run[fi][rr] = 0.f; }

    for (int chunk = 0; chunk < 8; ++chunk) {
        __syncthreads();   // protect Bs (prev MFMA) and cmw/csw (prev merge reads)
        #pragma unroll
        for (int i = 0; i < 4; ++i) {
            int flat = tid + i * 256;
            int row = flat >> 4, col = (flat & 15) * 8;
            *(short8*)&Bs[row][col] = *(const short8*)(Bb + (size_t)(chunk * 64 + row) * D_ + col);
        }
        __syncthreads();

        float4v acc[2][2] = {};
        #pragma unroll
        for (int ks = 0; ks < 128; ks += 32) {
            short8 af0 = *(const short8*)&As[wm * 32 + l15][ks + quad * 8];
            short8 af1 = *(const short8*)&As[wm * 32 + 16 + l15][ks + quad * 8];
            short8 bf0 = *(const short8*)&Bs[wn * 32 + l15][ks + quad * 8];
            short8 bf1 = *(const short8*)&Bs[wn * 32 + 16 + l15][ks + quad * 8];
            acc[0][0] = __builtin_amdgcn_mfma_f32_16x16x32_bf16(af0, bf0, acc[0][0], 0, 0, 0);
            acc[0][1] = __builtin_amdgcn_mfma_f32_16x16x32_bf16(af0, bf1, acc[0][1], 0, 0, 0);
            acc[1][0] = __builtin_amdgcn_mfma_f32_16x16x32_bf16(af1, bf0, acc[1][0], 0, 0, 0);
            acc[1][1] = __builtin_amdgcn_mfma_f32_16x16x32_bf16(af1, bf1, acc[1][1], 0, 0, 0);
        }

        // bias + store S + stats
        float v[2][2][4];
        #pragma unroll
        for (int fi = 0; fi < 2; ++fi)
            #pragma unroll
            for (int fj = 0; fj < 2; ++fj)
                #pragma unroll
                for (int rr = 0; rr < 4; ++rr) {
                    int mloc = wm * 32 + fi * 16 + quad * 4 + rr;
                    float x = acc[fi][fj][rr] + sbias[mloc];
                    v[fi][fj][rr] = x;
                    int nloc = wn * 32 + fj * 16 + l15;
                    Sbf[((size_t)(b * CL_ + m0 + mloc)) * QL_ + chunk * 64 + nloc] = f2bf(x);
                }

        // row running update (per lane: rows (fi,rr), cols fj pair)
        #pragma unroll
        for (int fi = 0; fi < 2; ++fi)
            #pragma unroll
            for (int rr = 0; rr < 4; ++rr) {
                float v0 = v[fi][0][rr], v1 = v[fi][1][rr];
                float nm = fmaxf(rm_run[fi][rr], fmaxf(v0, v1));
                rs_run[fi][rr] = rs_run[fi][rr] * __expf(rm_run[fi][rr] - nm)
                               + __expf(v0 - nm) + __expf(v1 - nm);
                rm_run[fi][rr] = nm;
            }

        // column partials: per lane per fj over its 8 rows, then quad butterfly
        #pragma unroll
        for (int fj = 0; fj < 2; ++fj) {
            float cm = v[0][fj][0];
            #pragma unroll
            for (int fi = 0; fi < 2; ++fi)
                #pragma unroll
                for (int rr = 0; rr < 4; ++rr) cm = fmaxf(cm, v[fi][fj][rr]);
            float cs = 0.f;
            #pragma unroll
            for (int fi = 0; fi < 2; ++fi)
                #pragma unroll
                for (int rr = 0; rr < 4; ++rr) cs += __expf(v[fi][fj][rr] - cm);
            #pragma unroll
            for (int off = 16; off <= 32; off <<= 1) {
                float om = __shfl_xor(cm, off);
                float os = __shfl_xor(cs, off);
                float nm = fmaxf(cm, om);
                cs = cs * __expf(cm - nm) + os * __expf(om - nm);
                cm = nm;
            }
            if (quad == 0) {
                int col = wn * 32 + fj * 16 + l15;
                cmw[wm][col] = cm;
                csw[wm][col] = cs;
            }
        }
        __syncthreads();
        if (tid < 64) {
            float m0v = cmw[0][tid], s0v = csw[0][tid];
            float m1v = cmw[1][tid], s1v = csw[1][tid];
            float nm = fmaxf(m0v, m1v);
            float ss = s0v * __expf(m0v - nm) + s1v * __expf(m1v - nm);
            size_t pi = ((size_t)(b * 16 + mt)) * QL_ + chunk * 64 + tid;
            pcmax[pi] = nm;
            pcsum[pi] = ss;
        }
    }

    // finalize row stats: butterfly over l15, then cross-wn merge via LDS
    #pragma unroll
    for (int off = 1; off <= 8; off <<= 1)
        #pragma unroll
        for (int fi = 0; fi < 2; ++fi)
            #pragma unroll
            for (int rr = 0; rr < 4; ++rr) {
                float om = __shfl_xor(rm_run[fi][rr], off);
                float os = __shfl_xor(rs_run[fi][rr], off);
                float nm = fmaxf(rm_run[fi][rr], om);
                rs_run[fi][rr] = rs_run[fi][rr] * __expf(rm_run[fi][rr] - nm)
                               + os * __expf(om - nm);
                rm_run[fi][rr] = nm;
            }
    if (l15 == 0) {
        #pragma unroll
        for (int fi = 0; fi < 2; ++fi)
            #pragma unroll
            for (int rr = 0; rr < 4; ++rr) {
                int m = wm * 32 + fi * 16 + quad * 4 + rr;
                rmw[wn][m] = rm_run[fi][rr];
                rsw[wn][m] = rs_run[fi][rr];
            }
    }
    __syncthreads();
    if (tid < 64) {
        float m0v = rmw[0][tid], s0v = rsw[0][tid];
        float m1v = rmw[1][tid], s1v = rsw[1][tid];
        float nm = fmaxf(m0v, m1v);
        float ss = s0v * __expf(m0v - nm) + s1v * __expf(m1v - nm);
        rmax[b * CL_ + m0 + tid] = nm;
        rinv[b * CL_ + m0 + tid] = 1.0f / ss;
    }
}

__global__ __launch_bounds__(256) void k_col_reduce(const float* __restrict__ pcmax,
                                                    const float* __restrict__ pcsum,
                                                    float* __restrict__ cmax,
                                                    float* __restrict__ cinv) {
    int g = blockIdx.x * 256 + threadIdx.x;
    int b = g >> 9, q = g & (QL_ - 1);
    float M = -1e30f, SS = 0.f;
    #pragma unroll
    for (int ch = 0; ch < 16; ++ch) {
        size_t idx = ((size_t)(b * 16 + ch)) * QL_ + q;
        float m = pcmax[idx], s = pcsum[idx];
        float nM = fmaxf(M, m);
        SS = SS * __expf(M - nM) + s * __expf(m - nM);
        M = nM;
    }
    cmax[g] = M;
    cinv[g] = 1.0f / SS;
}

// ---------------------------------------------------------------------------
// G_P: Pbf[d,q] = sum_c Cbf[d,c] * S2[c,q], S2 on-the-fly (exp + LDS transpose).
// Tile M=128 x N=32 q, K=CL, BK=64.  Plain dim3 grid.
// ---------------------------------------------------------------------------
__global__ __launch_bounds__(256) void k_gp(const unsigned short* __restrict__ Cbf,
                                            const unsigned short* __restrict__ Sbf,
                                            const float* __restrict__ cmax,
                                            const float* __restrict__ cinv,
                                            unsigned short* __restrict__ Pbf) {
    int b  = blockIdx.y;
    int q0 = blockIdx.x * 32;

    int tid  = threadIdx.x;
    int lane = tid & 63, wave = tid >> 6;
    int quad = lane >> 4, l15 = lane & 15;

    __shared__ __align__(16) short As[128][72];
    __shared__ __align__(16) short Bs[32][72];
    __shared__ float scm[32], sci[32];

    if (tid < 32) {
        scm[tid] = cmax[b * QL_ + q0 + tid];
        sci[tid] = cinv[b * QL_ + q0 + tid];
    }
    __syncthreads();

    const unsigned short* Cb = Cbf + (size_t)b * D_ * CL_;
    const unsigned short* Sb = Sbf + (size_t)b * CL_ * QL_;

    int arow = tid >> 3;
    int acol = (tid & 7) * 8;
    int srow = tid >> 4;
    int uq   = tid & 15;

    float4v acc[2][2] = {};

    for (int k0 = 0; k0 < CL_; k0 += 64) {
        #pragma unroll
        for (int p = 0; p < 4; ++p) {
            int row = p * 32 + arow;
            *(short8*)&As[row][acol] = *(const short8*)(Cb + (size_t)row * CL_ + k0 + acol);
        }
        #pragma unroll
        for (int p = 0; p < 4; ++p) {
            int crow = p * 16 + srow;
            unsigned int raw = *(const unsigned int*)(Sb + (size_t)(k0 + crow) * QL_ + q0 + 2 * uq);
            float v0 = __expf(bf2f((unsigned short)(raw & 0xFFFF)) - scm[2 * uq]) * sci[2 * uq];
            float v1 = __expf(bf2f((unsigned short)(raw >> 16)) - scm[2 * uq + 1]) * sci[2 * uq + 1];
            Bs[2 * uq][crow]     = (short)f2bf(v0);
            Bs[2 * uq + 1][crow] = (short)f2bf(v1);
        }
        __syncthreads();
        #pragma unroll
        for (int ks = 0; ks < 64; ks += 32) {
            short8 a0 = *(const short8*)&As[wave * 32 + l15][ks + quad * 8];
            short8 a1 = *(const short8*)&As[wave * 32 + 16 + l15][ks + quad * 8];
            short8 b0 = *(const short8*)&Bs[l15][ks + quad * 8];
            short8 b1 = *(const short8*)&Bs[16 + l15][ks + quad * 8];
            acc[0][0] = __builtin_amdgcn_mfma_f32_16x16x32_bf16(a0, b0, acc[0][0], 0, 0, 0);
            acc[0][1] = __builtin_amdgcn_mfma_f32_16x16x32_bf16(a0, b1, acc[0][1], 0, 0, 0);
            acc[1][0] = __builtin_amdgcn_mfma_f32_16x16x32_bf16(a1, b0, acc[1][0], 0, 0, 0);
            acc[1][1] = __builtin_amdgcn_mfma_f32_16x16x32_bf16(a1, b1, acc[1][1], 0, 0, 0);
        }
        __syncthreads();
    }

    #pragma unroll
    for (int fi = 0; fi < 2; ++fi)
        #pragma unroll
        for (int fj = 0; fj < 2; ++fj)
            #pragma unroll
            for (int rr = 0; rr < 4; ++rr) {
                int d = wave * 32 + fi * 16 + quad * 4 + rr;
                int q = q0 + fj * 16 + l15;
                Pbf[((size_t)(b * D_ + d)) * QL_ + q] = f2bf(acc[fi][fj][rr]);
            }
}

// ---------------------------------------------------------------------------
// k_av<PLANE>: Out[d,c] = sum_q A[d,q]*S1[c,q], S1 on-the-fly from Sbf+stats.
// PLANE 0 (A=Qbf): writes out planes 0 (Ct), 1 (At), 2 (Ct*At).
// PLANE 1 (A=Pbf): writes out plane 3 (Ct*Bmt).
// ---------------------------------------------------------------------------
template <int PLANE>
__global__ __launch_bounds__(256) void k_av(const unsigned short* __restrict__ A,
                                            const unsigned short* __restrict__ Sbf,
                                            const float* __restrict__ rmax,
                                            const float* __restrict__ rinv,
                                            const float* __restrict__ C,
                                            float* __restrict__ out) {
    int b  = blockIdx.y;
    int n0 = blockIdx.x * 32;

    int tid  = threadIdx.x;
    int lane = tid & 63, wave = tid >> 6;
    int quad = lane >> 4, l15 = lane & 15;

    __shared__ __align__(16) short As[128][72];
    __shared__ __align__(16) short Bs[32][72];
    __shared__ float srm[32], sri[32];

    if (tid < 32) {
        srm[tid] = rmax[b * CL_ + n0 + tid];
        sri[tid] = rinv[b * CL_ + n0 + tid];
    }
    __syncthreads();

    const unsigned short* Ab = A + (size_t)b * D_ * QL_;
    const unsigned short* Sb = Sbf + ((size_t)(b * CL_ + n0)) * QL_;

    int arow = tid >> 3;
    int acol = (tid & 7) * 8;

    float4v acc[2][2] = {};

    for (int k0 = 0; k0 < QL_; k0 += 64) {
        #pragma unroll
        for (int p = 0; p < 4; ++p) {
            int row = p * 32 + arow;
            *(short8*)&As[row][acol] = *(const short8*)(Ab + (size_t)row * QL_ + k0 + acol);
        }
        {
            int brow = tid >> 3;
            uint4 raw = *(const uint4*)(Sb + (size_t)brow * QL_ + k0 + acol);
            unsigned int rw[4] = {raw.x, raw.y, raw.z, raw.w};
            float rm = srm[brow], ri = sri[brow];
            short8 v;
            #pragma unroll
            for (int j = 0; j < 8; ++j) {
                unsigned short bits = (unsigned short)((rw[j >> 1] >> ((j & 1) * 16)) & 0xFFFF);
                v[j] = (short)f2bf(__expf(bf2f(bits) - rm) * ri);
            }
            *(short8*)&Bs[brow][acol] = v;
        }
        __syncthreads();
        #pragma unroll
        for (int ks = 0; ks < 64; ks += 32) {
            short8 a0 = *(const short8*)&As[wave * 32 + l15][ks + quad * 8];
            short8 a1 = *(const short8*)&As[wave * 32 + 16 + l15][ks + quad * 8];
            short8 b0 = *(const short8*)&Bs[l15][ks + quad * 8];
            short8 b1 = *(const short8*)&Bs[16 + l15][ks + quad * 8];
            acc[0][0] = __builtin_amdgcn_mfma_f32_16x16x32_bf16(a0, b0, acc[0][0], 0, 0, 0);
            acc[0][1] = __builtin_amdgcn_mfma_f32_16x16x32_bf16(a0, b1, acc[0][1], 0, 0, 0);
            acc[1][0] = __builtin_amdgcn_mfma_f32_16x16x32_bf16(a1, b0, acc[1][0], 0, 0, 0);
            acc[1][1] = __builtin_amdgcn_mfma_f32_16x16x32_bf16(a1, b1, acc[1][1], 0, 0, 0);
        }
        __syncthreads();
    }

    #pragma unroll
    for (int fi = 0; fi < 2; ++fi)
        #pragma unroll
        for (int fj = 0; fj < 2; ++fj)
            #pragma unroll
            for (int rr = 0; rr < 4; ++rr) {
                int d = wave * 32 + fi * 16 + quad * 4 + rr;
                int c = n0 + fj * 16 + l15;
                float ct = C[((size_t)(b * D_ + d)) * CL_ + c];
                float v  = acc[fi][fj][rr];
                size_t ob = ((size_t)(b * 4 * D_ + d)) * CL_ + c;
                if (PLANE == 0) {
                    out[ob]                        = ct;
                    out[ob + (size_t)D_ * CL_]     = v;
                    out[ob + 2 * (size_t)D_ * CL_] = ct * v;
                } else {
                    out[ob + 3 * (size_t)D_ * CL_] = ct * v;
                }
            }
}

// ---------------------------------------------------------------------------
// Launch. Workspace (~65.6 MB): Ubf 8.4, Qtbf 4.2, Qbf 4.2, Cbf 8.4, Pbf 4.2,
// Sbf 33.6, stats ~2.6 MB.
// ---------------------------------------------------------------------------
extern "C" void kernel_launch(void* const* d_in, const int* in_sizes, int n_in,
                              void* d_out, int out_size, void* d_ws, size_t ws_size,
                              hipStream_t stream) {
    const float* C = (const float*)d_in[0];
    const float* Q = (const float*)d_in[1];
    const float* W = (const float*)d_in[2];
    float* out = (float*)d_out;

    unsigned short* Ubf  = (unsigned short*)d_ws;
    unsigned short* Qtbf = Ubf  + (size_t)B_ * CL_ * D_;
    unsigned short* Qbf  = Qtbf + (size_t)B_ * QL_ * D_;
    unsigned short* Cbf  = Qbf  + (size_t)B_ * D_ * QL_;
    unsigned short* Pbf  = Cbf  + (size_t)B_ * D_ * CL_;
    unsigned short* Sbf  = Pbf  + (size_t)B_ * D_ * QL_;
    float* bias  = (float*)(Sbf + (size_t)B_ * CL_ * QL_);
    float* rmax  = bias  + (size_t)B_ * CL_;
    float* rinv  = rmax  + (size_t)B_ * CL_;
    float* cmax  = rinv  + (size_t)B_ * CL_;
    float* cinv  = cmax  + (size_t)B_ * QL_;
    float* pcmax = cinv  + (size_t)B_ * QL_;
    float* pcsum = pcmax + (size_t)B_ * 16 * QL_;

    k_u_bias<<<dim3(CL_ / 32, B_), 256, 0, stream>>>(C, W, Ubf, bias, Cbf);
    k_qt<<<dim3(QL_ / 64, D_ / 64, B_), 256, 0, stream>>>(Q, Qtbf, Qbf);
    k_gs2<<<dim3(16, B_), 256, 0, stream>>>(Ubf, Qtbf, bias, Sbf, rmax, rinv, pcmax, pcsum);
    k_col_reduce<<<B_ * QL_ / 256, 256, 0, stream>>>(pcmax, pcsum, cmax, cinv);
    k_gp<<<dim3(QL_ / 32, B_), 256, 0, stream>>>(Cbf, Sbf, cmax, cinv, Pbf);
    k_av<0><<<dim3(CL_ / 32, B_), 256, 0, stream>>>(Qbf, Sbf, rmax, rinv, C, out);
    k_av<1><<<dim3(CL_ / 32, B_), 256, 0, stream>>>(Pbf, Sbf, rmax, rinv, C, out);
}